// Round 6
// baseline (564.080 us; speedup 1.0000x reference)
//
#include <hip/hip_runtime.h>
#include <hip/hip_bf16.h>

#define D 128

typedef __attribute__((ext_vector_type(8))) __bf16 bf16x8;
typedef __attribute__((ext_vector_type(4))) float f32x4;
typedef __attribute__((ext_vector_type(4))) short s16x4;
typedef __attribute__((ext_vector_type(8))) short s16x8;

static __device__ __forceinline__ short f2bf(float f) {
    union { float f; unsigned u; } in; in.f = f;
    unsigned u = in.u;
    u += 0x7fffu + ((u >> 16) & 1u);   // round-to-nearest-even
    return (short)(u >> 16);
}

// ======== LEAN PREPROCESSING: two-pass counting sort by dst ========
// (r2/r5 showed intra-node edge order is irrelevant to k_layer perf, so the
// old slice-ordered bucket/staging/build chain was pure overhead: ~85MB of
// traffic vs ~27MB here, and 5 kernels+memset vs 4 tiny kernels+memset.)

// pass 1: per-dst edge counts (device atomics on 400KB table, L2-resident)
__global__ void k_hist(const int* __restrict__ dst, int* __restrict__ cnt, int E) {
    int i = blockIdx.x * 256 + threadIdx.x;
    if (i < E) atomicAdd(&cnt[dst[i]], 1);
}

// scan level 1: 256-entry local exclusive scans -> row_ptr; block sums -> part
__global__ void k_scan1(const int* __restrict__ cnt, int* __restrict__ row_ptr,
                        int* __restrict__ part, int N) {
    __shared__ int sm[256];
    const int t = threadIdx.x;
    const int i = blockIdx.x * 256 + t;
    int v = (i < N) ? cnt[i] : 0;
    sm[t] = v;
    __syncthreads();
    for (int off = 1; off < 256; off <<= 1) {
        int x = (t >= off) ? sm[t - off] : 0;
        __syncthreads();
        sm[t] += x;
        __syncthreads();
    }
    if (i < N) row_ptr[i] = sm[t] - v;          // local exclusive
    if (t == 255) part[blockIdx.x] = sm[255];   // block total
}

// scan level 2: single block scans the ~391 block totals (exclusive, in place)
__global__ void k_scan2(int* __restrict__ part, int nb) {
    __shared__ int sm[512];
    const int t = threadIdx.x;
    int v = (t < nb) ? part[t] : 0;
    sm[t] = v;
    __syncthreads();
    for (int off = 1; off < 512; off <<= 1) {
        int x = (t >= off) ? sm[t - off] : 0;
        __syncthreads();
        sm[t] += x;
        __syncthreads();
    }
    if (t < nb) part[t] = sm[t] - v;            // exclusive base per block
}

// scan level 3: add bases; init scatter cursors; dinv = rsqrt(deg+1) (self-loop)
__global__ void k_scan3(const int* __restrict__ cnt, int* __restrict__ row_ptr,
                        const int* __restrict__ part, int* __restrict__ cur,
                        float* __restrict__ dinv, int N, int E) {
    const int i = blockIdx.x * 256 + threadIdx.x;
    if (i < N) {
        int r = row_ptr[i] + part[blockIdx.x];
        row_ptr[i] = r;
        cur[i] = r;
        dinv[i] = rsqrtf((float)cnt[i] + 1.0f);
    }
    if (blockIdx.x == 0 && threadIdx.x == 0) row_ptr[N] = E;
}

// pass 2: scatter src ids into per-dst contiguous csr regions
__global__ void k_scatter(const int* __restrict__ src, const int* __restrict__ dst,
                          int* __restrict__ cur, int* __restrict__ csr_src, int E) {
    int i = blockIdx.x * 256 + threadIdx.x;
    if (i >= E) return;
    int pos = atomicAdd(&cur[dst[i]], 1);
    csr_src[pos] = src[i];
}

// ---- batch is SORTED: segment starts AND counts via binary search ----
__global__ void k_gseg(const int* __restrict__ batch, int* __restrict__ gstart,
                       int* __restrict__ gcnt, int N, int B) {
    int g = blockIdx.x * blockDim.x + threadIdx.x;
    if (g > B) return;
    int lo = 0, hi = N;
    while (lo < hi) {
        int mid = (lo + hi) >> 1;
        if (batch[mid] < g) lo = mid + 1; else hi = mid;
    }
    gstart[g] = lo;
    if (g < B) {
        int lo2 = lo, hi2 = N;
        while (lo2 < hi2) {
            int mid = (lo2 + hi2) >> 1;
            if (batch[mid] < g + 1) lo2 = mid + 1; else hi2 = mid;
        }
        gcnt[g] = lo2 - lo;
    }
}

// ---- x' = dinv[i] * x  -> bf16 (pre-scaled feature rows) ----
__global__ void k_cvt_x(const float* __restrict__ x, const float* __restrict__ dinv,
                        short* __restrict__ xb, int total4) {
    int i = blockIdx.x * blockDim.x + threadIdx.x;
    if (i < total4) {
        float d = dinv[i >> 5];
        float4 v = ((const float4*)x)[i];
        s16x4 o;
        o.x = f2bf(v.x * d); o.y = f2bf(v.y * d);
        o.z = f2bf(v.z * d); o.w = f2bf(v.w * d);
        ((s16x4*)xb)[i] = o;
    }
}

// ---- conv_w: fp32 [L][k][n] -> bf16 transposed [L][n][k] ----
__global__ void k_cvt_w(const float* __restrict__ W, short* __restrict__ Wt, int total) {
    int i = blockIdx.x * blockDim.x + threadIdx.x;
    if (i < total) {
        int l = i >> 14;
        int rem = i & 16383;
        int n = rem >> 7;
        int k = rem & 127;
        Wt[i] = f2bf(W[(l << 14) + (k << 7) + n]);
    }
}

// ---- FUSED layer (r3-proven, flat row_ptr): 16 nodes/block + 8-deep chains ----
// 16 concurrent nodes/block (1 per 16-lane group, sequential ids) -> 4KB LDS
// tile -> 1 barrier -> cooperative 16x128 MFMA GEMM (wave w = 32 cols).
// Phase-1 main loop: 8 row-gathers in flight per group, next iteration's
// indices software-pipelined. This kernel is pinned at ~84us across six
// structural variants (r0-r5) -- random-gather line-rate floor; left as is.
// mode 0: hout[r] = bf16( relu(C + b) * dinv[r] );  mode 1: hrelu[r] = fp32 relu(C+b)
__global__ __launch_bounds__(256) void k_layer(
    const short* __restrict__ hin, const int* __restrict__ row_ptr,
    const int* __restrict__ csr_src, const float* __restrict__ dinv,
    const short* __restrict__ Wt, const float* __restrict__ bias,
    short* __restrict__ hout, float* __restrict__ hrelu, int N, int mode)
{
    __shared__ __align__(16) short tile[16 * 128];   // 4 KB, swizzled 16B chunks
    const int tid = threadIdx.x;
    const int wave = tid >> 6;
    const int lane = tid & 63;
    const int group = lane >> 4;
    const int lg = lane & 15;
    const int off = lg * 8;
    const int node_base = blockIdx.x * 16;
    const int r = wave * 4 + group;          // tile row this group owns (0..15)
    const int i = node_base + r;

    // ---- phase 1: aggregate one node per group (16 concurrent per block) ----
    short* dstp = &tile[r * 128 + ((lg ^ (r & 7)) << 3)];
    if (i < N) {
        float acc[8];
        bf16x8 v = *(const bf16x8*)(hin + (size_t)i * D + off);
        #pragma unroll
        for (int k = 0; k < 8; k++) acc[k] = (float)v[k];

        int t = row_ptr[i];
        const int end = row_ptr[i + 1];
        const int nfull = (end - t) >> 3;    // full 8-chains

        int i0, i1, i2, i3, i4, i5, i6, i7;
        if (nfull > 0) {
            i0 = csr_src[t + 0]; i1 = csr_src[t + 1];
            i2 = csr_src[t + 2]; i3 = csr_src[t + 3];
            i4 = csr_src[t + 4]; i5 = csr_src[t + 5];
            i6 = csr_src[t + 6]; i7 = csr_src[t + 7];
        }
        #pragma unroll 1
        for (int c = 0; c < nfull; c++) {
            bf16x8 v0 = *(const bf16x8*)(hin + (size_t)i0 * D + off);
            bf16x8 v1 = *(const bf16x8*)(hin + (size_t)i1 * D + off);
            bf16x8 v2 = *(const bf16x8*)(hin + (size_t)i2 * D + off);
            bf16x8 v3 = *(const bf16x8*)(hin + (size_t)i3 * D + off);
            bf16x8 v4 = *(const bf16x8*)(hin + (size_t)i4 * D + off);
            bf16x8 v5 = *(const bf16x8*)(hin + (size_t)i5 * D + off);
            bf16x8 v6 = *(const bf16x8*)(hin + (size_t)i6 * D + off);
            bf16x8 v7 = *(const bf16x8*)(hin + (size_t)i7 * D + off);
            t += 8;
            if (c + 1 < nfull) {             // prefetch next indices while rows fly
                i0 = csr_src[t + 0]; i1 = csr_src[t + 1];
                i2 = csr_src[t + 2]; i3 = csr_src[t + 3];
                i4 = csr_src[t + 4]; i5 = csr_src[t + 5];
                i6 = csr_src[t + 6]; i7 = csr_src[t + 7];
            }
            #pragma unroll
            for (int k = 0; k < 8; k++)
                acc[k] += ((((float)v0[k] + (float)v1[k]) + ((float)v2[k] + (float)v3[k]))
                         + (((float)v4[k] + (float)v5[k]) + ((float)v6[k] + (float)v7[k])));
        }
        for (; t + 4 <= end; t += 4) {       // 4-deep tail
            int j0 = csr_src[t + 0], j1 = csr_src[t + 1];
            int j2 = csr_src[t + 2], j3 = csr_src[t + 3];
            bf16x8 v0 = *(const bf16x8*)(hin + (size_t)j0 * D + off);
            bf16x8 v1 = *(const bf16x8*)(hin + (size_t)j1 * D + off);
            bf16x8 v2 = *(const bf16x8*)(hin + (size_t)j2 * D + off);
            bf16x8 v3 = *(const bf16x8*)(hin + (size_t)j3 * D + off);
            #pragma unroll
            for (int k = 0; k < 8; k++)
                acc[k] += (((float)v0[k] + (float)v1[k]) + ((float)v2[k] + (float)v3[k]));
        }
        for (; t < end; t++) {               // scalar tail (<=3)
            int j0 = csr_src[t];
            bf16x8 v0 = *(const bf16x8*)(hin + (size_t)j0 * D + off);
            #pragma unroll
            for (int k = 0; k < 8; k++) acc[k] += (float)v0[k];
        }

        const float di = dinv[i];
        s16x8 o;
        #pragma unroll
        for (int k = 0; k < 8; k++) o[k] = f2bf(acc[k] * di);
        *(s16x8*)dstp = o;
    } else {
        s16x8 z = {0, 0, 0, 0, 0, 0, 0, 0};
        *(s16x8*)dstp = z;
    }
    __syncthreads();

    // ---- phase 2: cooperative GEMM; wave w computes cols [w*32, w*32+32) ----
    bf16x8 afrag[4];
    #pragma unroll
    for (int kt = 0; kt < 4; kt++)
        afrag[kt] = *(const bf16x8*)(&tile[lg * 128 + (((group + 4 * kt) ^ (lg & 7)) << 3)]);

    f32x4 acc2[2];
    #pragma unroll
    for (int nt = 0; nt < 2; nt++) { f32x4 z = {0.f, 0.f, 0.f, 0.f}; acc2[nt] = z; }
    #pragma unroll
    for (int nt = 0; nt < 2; nt++) {
        const short* bp = Wt + (size_t)(wave * 32 + nt * 16 + lg) * D + group * 8;
        #pragma unroll
        for (int kt = 0; kt < 4; kt++) {
            bf16x8 b = *(const bf16x8*)(bp + kt * 32);
            acc2[nt] = __builtin_amdgcn_mfma_f32_16x16x32_bf16(afrag[kt], b, acc2[nt], 0, 0, 0);
        }
    }

    // C/D layout: col = lane&15, row = (lane>>4)*4 + reg
    float bcol[2];
    #pragma unroll
    for (int nt = 0; nt < 2; nt++) bcol[nt] = bias[wave * 32 + nt * 16 + lg];
    const int row0 = node_base + group * 4;
    #pragma unroll
    for (int i2 = 0; i2 < 4; i2++) {
        int r2 = row0 + i2;
        if (r2 < N) {
            if (mode == 0) {
                float dr = dinv[r2];
                #pragma unroll
                for (int nt = 0; nt < 2; nt++) {
                    int col = wave * 32 + nt * 16 + lg;
                    float val = fmaxf(acc2[nt][i2] + bcol[nt], 0.0f);
                    hout[(size_t)r2 * D + col] = f2bf(val * dr);
                }
            } else {
                #pragma unroll
                for (int nt = 0; nt < 2; nt++) {
                    int col = wave * 32 + nt * 16 + lg;
                    hrelu[(size_t)r2 * D + col] = fmaxf(acc2[nt][i2] + bcol[nt], 0.0f);
                }
            }
        }
    }
}

// ---- segmented pooling, 4-way row-split per graph for latency hiding ----
__global__ __launch_bounds__(256) void k_pool(const float* __restrict__ hrelu,
                                              const int* __restrict__ gstart,
                                              const int* __restrict__ gcnt,
                                              float* __restrict__ pmax,
                                              float* __restrict__ psum, int B) {
    int g = blockIdx.x >> 2;
    int q = blockIdx.x & 3;
    int c = threadIdx.x & 127;
    int p = threadIdx.x >> 7;
    int start = gstart[g];
    int endr = start + gcnt[g];

    float mx0 = 0.f, mx1 = 0.f, sm0 = 0.f, sm1 = 0.f;
    int r = start + q * 2 + p;
    for (; r + 8 < endr; r += 16) {
        float v0 = hrelu[(size_t)r * D + c];
        float v1 = hrelu[(size_t)(r + 8) * D + c];
        mx0 = fmaxf(mx0, v0); sm0 += v0;
        mx1 = fmaxf(mx1, v1); sm1 += v1;
    }
    if (r < endr) {
        float v0 = hrelu[(size_t)r * D + c];
        mx0 = fmaxf(mx0, v0); sm0 += v0;
    }
    float mx = fmaxf(mx0, mx1), sm = sm0 + sm1;

    __shared__ float smx[128], ssm[128];
    if (p == 1) { smx[c] = mx; ssm[c] = sm; }
    __syncthreads();
    if (p == 0) {
        pmax[((size_t)q * B + g) * D + c] = fmaxf(mx, smx[c]);
        psum[((size_t)q * B + g) * D + c] = sm + ssm[c];
    }
}

// ---- final: combine 4 partials; out[g] = [gmax, gsum/cnt, gsum] @ out_w + out_b ----
__global__ void k_final(const float* __restrict__ pmax, const float* __restrict__ psum,
                        const int* __restrict__ gcnt, const float* __restrict__ ow,
                        const float* __restrict__ ob, float* __restrict__ out, int B) {
    int g = blockIdx.x;
    int t = threadIdx.x;  // 64
    float part[10];
    #pragma unroll
    for (int o = 0; o < 10; o++) part[o] = 0.f;
    float invc = 1.0f / fmaxf((float)gcnt[g], 1.0f);
    for (int k = t; k < 3 * D; k += 64) {
        int c = (k < D) ? k : ((k < 2 * D) ? k - D : k - 2 * D);
        float pk;
        if (k < D) {
            float m = pmax[(size_t)g * D + c];
            #pragma unroll
            for (int q = 1; q < 4; q++) m = fmaxf(m, pmax[((size_t)q * B + g) * D + c]);
            pk = m;
        } else {
            float s = psum[(size_t)g * D + c];
            #pragma unroll
            for (int q = 1; q < 4; q++) s += psum[((size_t)q * B + g) * D + c];
            pk = (k < 2 * D) ? s * invc : s;
        }
        const float* w = ow + k * 10;
        #pragma unroll
        for (int o = 0; o < 10; o++) part[o] += pk * w[o];
    }
    #pragma unroll
    for (int off = 32; off > 0; off >>= 1)
        #pragma unroll
        for (int o = 0; o < 10; o++) part[o] += __shfl_down(part[o], off, 64);
    if (t == 0)
        #pragma unroll
        for (int o = 0; o < 10; o++) out[g * 10 + o] = part[o] + ob[o];
}

extern "C" void kernel_launch(void* const* d_in, const int* in_sizes, int n_in,
                              void* d_out, int out_size, void* d_ws, size_t ws_size,
                              hipStream_t stream) {
    const float* x     = (const float*)d_in[0];
    const int*   ei    = (const int*)d_in[1];
    const int*   batch = (const int*)d_in[2];
    const float* convw = (const float*)d_in[3];
    const float* convb = (const float*)d_in[4];
    const float* outw  = (const float*)d_in[5];
    const float* outb  = (const float*)d_in[6];
    float* out = (float*)d_out;

    const int N = in_sizes[0] / D;        // 100000
    const int E = in_sizes[1] / 2;        // 1600000
    const int L = in_sizes[3] / (D * D);  // 3
    const int B = out_size / 10;          // 256

    const int* src = ei;
    const int* dst = ei + E;

    char* p = (char*)d_ws;
    auto alloc = [&](size_t bytes) { char* r = p; p += (bytes + 255) & ~255ull; return r; };
    short* hb0     = (short*)alloc((size_t)N * D * 2);      // ping-pong bf16 rows
    short* hb1     = (short*)alloc((size_t)N * D * 2);
    float* hrelu   = (float*)alloc((size_t)N * D * 4);      // fp32 last-layer relu
    short* Wt      = (short*)alloc((size_t)L * D * D * 2);  // bf16 W^T
    int*   row_ptr = (int*)alloc(((size_t)N + 1) * 4);
    int*   csr_src = (int*)alloc((size_t)E * 4);
    int*   cnt     = (int*)alloc((size_t)N * 4);            // per-dst edge counts
    int*   cur     = (int*)alloc((size_t)N * 4);            // scatter cursors
    int*   part    = (int*)alloc(1024 * 4);                 // scan block partials
    float* dinv    = (float*)alloc((size_t)N * 4);
    float* pmax    = (float*)alloc((size_t)4 * B * D * 4);
    float* psum    = (float*)alloc((size_t)4 * B * D * 4);
    int*   gcnt    = (int*)alloc((size_t)B * 4);
    int*   gstart  = (int*)alloc(((size_t)B + 1) * 4);

    const int nb = (N + 255) / 256;   // scan blocks (391)

    hipMemsetAsync(cnt, 0, (size_t)N * 4, stream);

    k_hist<<<(E + 255) / 256, 256, 0, stream>>>(dst, cnt, E);
    k_gseg<<<1, 512, 0, stream>>>(batch, gstart, gcnt, N, B);
    k_scan1<<<nb, 256, 0, stream>>>(cnt, row_ptr, part, N);
    k_scan2<<<1, 512, 0, stream>>>(part, nb);
    k_scan3<<<nb, 256, 0, stream>>>(cnt, row_ptr, part, cur, dinv, N, E);
    k_scatter<<<(E + 255) / 256, 256, 0, stream>>>(src, dst, cur, csr_src, E);
    k_cvt_x<<<((N * D / 4) + 255) / 256, 256, 0, stream>>>(x, dinv, hb0, N * D / 4);
    k_cvt_w<<<((L * D * D) + 255) / 256, 256, 0, stream>>>(convw, Wt, L * D * D);

    const int lblocks = (N + 15) / 16;
    // layer 0: hb0 -> hb1 ; layer 1: hb1 -> hb0 ; layer 2: hb0 -> hrelu
    k_layer<<<lblocks, 256, 0, stream>>>(hb0, row_ptr, csr_src, dinv, Wt,
                                         convb, hb1, hrelu, N, 0);
    k_layer<<<lblocks, 256, 0, stream>>>(hb1, row_ptr, csr_src, dinv, Wt + D * D,
                                         convb + D, hb0, hrelu, N, 0);
    k_layer<<<lblocks, 256, 0, stream>>>(hb0, row_ptr, csr_src, dinv, Wt + 2 * D * D,
                                         convb + 2 * D, hb1, hrelu, N, 1);

    k_pool<<<B * 4, 256, 0, stream>>>(hrelu, gstart, gcnt, pmax, psum, B);
    k_final<<<B, 64, 0, stream>>>(pmax, psum, gcnt, outw, outb, out, B);
}

// Round 8
// 484.619 us; speedup vs baseline: 1.1640x; 1.1640x over previous
//
#include <hip/hip_runtime.h>
#include <hip/hip_bf16.h>

#define D 128
#define NP 8           // src-range sub-buckets per dst (csr slice order)
#define DPB 64         // dst per coarse bucket (b = d>>6)
#define KPB (DPB * NP) // fine keys per bucket = 512
#define SUB 64         // sub-cursors per bucket
#define CAP_SUB 64     // staging capacity per (sub, bucket); mean 16

typedef __attribute__((ext_vector_type(8))) __bf16 bf16x8;
typedef __attribute__((ext_vector_type(4))) float f32x4;
typedef __attribute__((ext_vector_type(4))) short s16x4;
typedef __attribute__((ext_vector_type(8))) short s16x8;

static __device__ __forceinline__ short f2bf(float f) {
    union { float f; unsigned u; } in; in.f = f;
    unsigned u = in.u;
    u += 0x7fffu + ((u >> 16) & 1u);   // round-to-nearest-even
    return (short)(u >> 16);
}

// ---- phase 1: coarse-bucket edges; 100K sub-cursors kill contention ----
// pack: fineKey(9b: (d&63)*8 + (src>>14)) << 17 | src(17b)   [N < 2^17]
// (two-phase scatter: r6 proved single-pass random 4B scatter costs 125us
//  in 64B-line RMW traffic; staging confines writes to L2-local windows)
__global__ void k_bucket(const int* __restrict__ src, const int* __restrict__ dst,
                         int* __restrict__ bcnt, int* __restrict__ staging,
                         int E, int KBE) {
    int i = blockIdx.x * 256 + threadIdx.x;
    if (i >= E) return;
    int d = __builtin_nontemporal_load(dst + i);
    int s = __builtin_nontemporal_load(src + i);
    int b = d >> 6;
    int key = ((d & 63) << 3) | (s >> 14);
    int j = blockIdx.x & (SUB - 1);      // j%8 == heuristic XCD
    int slot = atomicAdd(&bcnt[j * KBE + b], 1);
    if (slot < CAP_SUB)
        __builtin_nontemporal_store((key << 17) | s,
                                    staging + ((size_t)j * KBE + b) * CAP_SUB + slot);
}

// ---- per-bucket totals (parallel, coalesced per-j stripes) ----
__global__ void k_btot(const int* __restrict__ bcnt, int* __restrict__ btot, int KBE) {
    int b = blockIdx.x * 256 + threadIdx.x;
    if (b >= KBE) return;
    int v = 0;
    #pragma unroll
    for (int j = 0; j < SUB; j++) {
        int c = bcnt[j * KBE + b];
        v += (c > CAP_SUB) ? CAP_SUB : c;
    }
    btot[b] = v;
}

// ---- exclusive scan of bucket totals (single block, chunked) ----
__global__ void k_bscan(const int* __restrict__ btot, int* __restrict__ bbase,
                        int* __restrict__ row_ptr, int nkeys, int KBE) {
    __shared__ int sm[512];
    __shared__ int carry;
    int t = threadIdx.x;
    if (t == 0) carry = 0;
    __syncthreads();
    for (int c0 = 0; c0 < KBE; c0 += 512) {
        int b = c0 + t;
        int v = (b < KBE) ? btot[b] : 0;
        sm[t] = v;
        __syncthreads();
        for (int off = 1; off < 512; off <<= 1) {
            int x = (t >= off) ? sm[t - off] : 0;
            __syncthreads();
            sm[t] += x;
            __syncthreads();
        }
        if (b < KBE) bbase[b] = sm[t] - v + carry;
        __syncthreads();
        if (t == 0) carry += sm[511];
        __syncthreads();
    }
    if (t == 0) { bbase[KBE] = carry; row_ptr[nkeys] = carry; }
}

// ---- phase 2: per-bucket fine CSR build in LDS; no binary search, no serial prefix ----
// thread t owns lane (t&3) of sub-region j = t>>2  (4 threads per sub, ~16 edges each)
__global__ __launch_bounds__(256) void k_build(
    const int* __restrict__ staging, const int* __restrict__ bcnt,
    const int* __restrict__ bbase, int* __restrict__ row_ptr,
    int* __restrict__ csr_src, float* __restrict__ dinv, int N, int KBE)
{
    const int b = blockIdx.x;
    const int tid = threadIdx.x;
    __shared__ int cnt[KPB];
    __shared__ int subn[SUB];
    __shared__ int chunkbuf[256];
    __shared__ int carry;

    if (tid < SUB) {
        int c = bcnt[tid * KBE + b];
        subn[tid] = (c > CAP_SUB) ? CAP_SUB : c;
    }
    for (int k = tid; k < KPB; k += 256) cnt[k] = 0;
    if (tid == 0) carry = 0;
    __syncthreads();

    const int base = bbase[b];
    const int nb = bbase[b + 1] - base;          // bucket total (from scan)
    const int j = tid >> 2, l4 = tid & 3;
    const int* __restrict__ sreg = staging + ((size_t)j * KBE + b) * CAP_SUB;
    const int sn = subn[j];

    // histogram over fine keys
    for (int e = l4; e < sn; e += 4)
        atomicAdd(&cnt[sreg[e] >> 17], 1);
    __syncthreads();

    // in-place exclusive scan of cnt[0..KPB)  (2 chunks of 256)
    #pragma unroll 1
    for (int c = 0; c < KPB / 256; c++) {
        int idx = c * 256 + tid;
        int v = cnt[idx];
        chunkbuf[tid] = v;
        __syncthreads();
        for (int off = 1; off < 256; off <<= 1) {
            int x = (tid >= off) ? chunkbuf[tid - off] : 0;
            __syncthreads();
            chunkbuf[tid] += x;
            __syncthreads();
        }
        cnt[idx] = chunkbuf[tid] - v + carry;
        __syncthreads();
        if (tid == 255) carry += chunkbuf[255];
        __syncthreads();
    }

    for (int k = tid; k < KPB; k += 256)
        row_ptr[(size_t)b * KPB + k] = base + cnt[k];
    for (int dl = tid; dl < DPB; dl += 256) {
        int d = b * DPB + dl;
        if (d < N) {
            int hi2 = (dl == DPB - 1) ? nb : cnt[(dl + 1) * NP];
            int deg = hi2 - cnt[dl * NP];
            dinv[d] = rsqrtf((float)deg + 1.0f);
        }
    }
    __syncthreads();

    // scatter into this bucket's contiguous csr region (LDS cursors)
    for (int e = l4; e < sn; e += 4) {
        int w = sreg[e];
        int slot = base + atomicAdd(&cnt[w >> 17], 1);
        csr_src[slot] = w & 0x1FFFF;
    }
}

// ---- batch is SORTED: segment starts AND counts via binary search ----
__global__ void k_gseg(const int* __restrict__ batch, int* __restrict__ gstart,
                       int* __restrict__ gcnt, int N, int B) {
    int g = blockIdx.x * blockDim.x + threadIdx.x;
    if (g > B) return;
    int lo = 0, hi = N;
    while (lo < hi) {
        int mid = (lo + hi) >> 1;
        if (batch[mid] < g) lo = mid + 1; else hi = mid;
    }
    gstart[g] = lo;
    if (g < B) {
        int lo2 = lo, hi2 = N;
        while (lo2 < hi2) {
            int mid = (lo2 + hi2) >> 1;
            if (batch[mid] < g + 1) lo2 = mid + 1; else hi2 = mid;
        }
        gcnt[g] = lo2 - lo;
    }
}

// ---- x' = dinv[i] * x  -> bf16 (pre-scaled feature rows) ----
__global__ void k_cvt_x(const float* __restrict__ x, const float* __restrict__ dinv,
                        short* __restrict__ xb, int total4) {
    int i = blockIdx.x * blockDim.x + threadIdx.x;
    if (i < total4) {
        float d = dinv[i >> 5];
        f32x4 v = __builtin_nontemporal_load((const f32x4*)x + i);
        s16x4 o;
        o.x = f2bf(v.x * d); o.y = f2bf(v.y * d);
        o.z = f2bf(v.z * d); o.w = f2bf(v.w * d);
        ((s16x4*)xb)[i] = o;
    }
}

// ---- conv_w: fp32 [L][k][n] -> bf16 transposed [L][n][k] ----
__global__ void k_cvt_w(const float* __restrict__ W, short* __restrict__ Wt, int total) {
    int i = blockIdx.x * blockDim.x + threadIdx.x;
    if (i < total) {
        int l = i >> 14;
        int rem = i & 16383;
        int n = rem >> 7;
        int k = rem & 127;
        Wt[i] = f2bf(W[(l << 14) + (k << 7) + n]);
    }
}

// ---- FUSED layer (r3 structure + NT hints on single-use streams) ----
// 16 nodes/block, 8-deep pipelined gather chains, 1 barrier, 16x128 MFMA GEMM.
// NEW vs r3: csr_src/row_ptr loads and hout/hrelu stores are NON-TEMPORAL.
// Theory: those streams cycle ~32MB/layer through the 4MB/XCD L2, evicting
// hin between its ~16x reuses. k_layer is latency-bound (miss-queue ~48 x
// avg-lat ~370cy); raising hin's L2 hit rate lowers avg latency directly.
// hin gathers, Wt, dinv keep normal caching.
// mode 0: hout[r] = bf16( relu(C + b) * dinv[r] );  mode 1: hrelu[r] = fp32 relu(C+b)
__global__ __launch_bounds__(256) void k_layer(
    const short* __restrict__ hin, const int* __restrict__ row_ptr,
    const int* __restrict__ csr_src, const float* __restrict__ dinv,
    const short* __restrict__ Wt, const float* __restrict__ bias,
    short* __restrict__ hout, float* __restrict__ hrelu, int N, int mode)
{
    __shared__ __align__(16) short tile[16 * 128];   // 4 KB, swizzled 16B chunks
    const int tid = threadIdx.x;
    const int wave = tid >> 6;
    const int lane = tid & 63;
    const int group = lane >> 4;
    const int lg = lane & 15;
    const int off = lg * 8;
    const int node_base = blockIdx.x * 16;
    const int r = wave * 4 + group;          // tile row this group owns (0..15)
    const int i = node_base + r;

    // ---- phase 1: aggregate one node per group (16 concurrent per block) ----
    short* dstp = &tile[r * 128 + ((lg ^ (r & 7)) << 3)];
    if (i < N) {
        float acc[8];
        bf16x8 v = *(const bf16x8*)(hin + (size_t)i * D + off);
        #pragma unroll
        for (int k = 0; k < 8; k++) acc[k] = (float)v[k];

        int t = __builtin_nontemporal_load(row_ptr + i * NP);
        const int end = __builtin_nontemporal_load(row_ptr + i * NP + NP);
        const int nfull = (end - t) >> 3;    // full 8-chains

        int i0, i1, i2, i3, i4, i5, i6, i7;
        if (nfull > 0) {
            i0 = __builtin_nontemporal_load(csr_src + t + 0);
            i1 = __builtin_nontemporal_load(csr_src + t + 1);
            i2 = __builtin_nontemporal_load(csr_src + t + 2);
            i3 = __builtin_nontemporal_load(csr_src + t + 3);
            i4 = __builtin_nontemporal_load(csr_src + t + 4);
            i5 = __builtin_nontemporal_load(csr_src + t + 5);
            i6 = __builtin_nontemporal_load(csr_src + t + 6);
            i7 = __builtin_nontemporal_load(csr_src + t + 7);
        }
        #pragma unroll 1
        for (int c = 0; c < nfull; c++) {
            bf16x8 v0 = *(const bf16x8*)(hin + (size_t)i0 * D + off);
            bf16x8 v1 = *(const bf16x8*)(hin + (size_t)i1 * D + off);
            bf16x8 v2 = *(const bf16x8*)(hin + (size_t)i2 * D + off);
            bf16x8 v3 = *(const bf16x8*)(hin + (size_t)i3 * D + off);
            bf16x8 v4 = *(const bf16x8*)(hin + (size_t)i4 * D + off);
            bf16x8 v5 = *(const bf16x8*)(hin + (size_t)i5 * D + off);
            bf16x8 v6 = *(const bf16x8*)(hin + (size_t)i6 * D + off);
            bf16x8 v7 = *(const bf16x8*)(hin + (size_t)i7 * D + off);
            t += 8;
            if (c + 1 < nfull) {             // prefetch next indices while rows fly
                i0 = __builtin_nontemporal_load(csr_src + t + 0);
                i1 = __builtin_nontemporal_load(csr_src + t + 1);
                i2 = __builtin_nontemporal_load(csr_src + t + 2);
                i3 = __builtin_nontemporal_load(csr_src + t + 3);
                i4 = __builtin_nontemporal_load(csr_src + t + 4);
                i5 = __builtin_nontemporal_load(csr_src + t + 5);
                i6 = __builtin_nontemporal_load(csr_src + t + 6);
                i7 = __builtin_nontemporal_load(csr_src + t + 7);
            }
            #pragma unroll
            for (int k = 0; k < 8; k++)
                acc[k] += ((((float)v0[k] + (float)v1[k]) + ((float)v2[k] + (float)v3[k]))
                         + (((float)v4[k] + (float)v5[k]) + ((float)v6[k] + (float)v7[k])));
        }
        for (; t + 4 <= end; t += 4) {       // 4-deep tail
            int j0 = __builtin_nontemporal_load(csr_src + t + 0);
            int j1 = __builtin_nontemporal_load(csr_src + t + 1);
            int j2 = __builtin_nontemporal_load(csr_src + t + 2);
            int j3 = __builtin_nontemporal_load(csr_src + t + 3);
            bf16x8 v0 = *(const bf16x8*)(hin + (size_t)j0 * D + off);
            bf16x8 v1 = *(const bf16x8*)(hin + (size_t)j1 * D + off);
            bf16x8 v2 = *(const bf16x8*)(hin + (size_t)j2 * D + off);
            bf16x8 v3 = *(const bf16x8*)(hin + (size_t)j3 * D + off);
            #pragma unroll
            for (int k = 0; k < 8; k++)
                acc[k] += (((float)v0[k] + (float)v1[k]) + ((float)v2[k] + (float)v3[k]));
        }
        for (; t < end; t++) {               // scalar tail (<=3)
            int j0 = __builtin_nontemporal_load(csr_src + t);
            bf16x8 v0 = *(const bf16x8*)(hin + (size_t)j0 * D + off);
            #pragma unroll
            for (int k = 0; k < 8; k++) acc[k] += (float)v0[k];
        }

        const float di = dinv[i];
        s16x8 o;
        #pragma unroll
        for (int k = 0; k < 8; k++) o[k] = f2bf(acc[k] * di);
        *(s16x8*)dstp = o;
    } else {
        s16x8 z = {0, 0, 0, 0, 0, 0, 0, 0};
        *(s16x8*)dstp = z;
    }
    __syncthreads();

    // ---- phase 2: cooperative GEMM; wave w computes cols [w*32, w*32+32) ----
    bf16x8 afrag[4];
    #pragma unroll
    for (int kt = 0; kt < 4; kt++)
        afrag[kt] = *(const bf16x8*)(&tile[lg * 128 + (((group + 4 * kt) ^ (lg & 7)) << 3)]);

    f32x4 acc2[2];
    #pragma unroll
    for (int nt = 0; nt < 2; nt++) { f32x4 z = {0.f, 0.f, 0.f, 0.f}; acc2[nt] = z; }
    #pragma unroll
    for (int nt = 0; nt < 2; nt++) {
        const short* bp = Wt + (size_t)(wave * 32 + nt * 16 + lg) * D + group * 8;
        #pragma unroll
        for (int kt = 0; kt < 4; kt++) {
            bf16x8 b = *(const bf16x8*)(bp + kt * 32);
            acc2[nt] = __builtin_amdgcn_mfma_f32_16x16x32_bf16(afrag[kt], b, acc2[nt], 0, 0, 0);
        }
    }

    // C/D layout: col = lane&15, row = (lane>>4)*4 + reg
    float bcol[2];
    #pragma unroll
    for (int nt = 0; nt < 2; nt++) bcol[nt] = bias[wave * 32 + nt * 16 + lg];
    const int row0 = node_base + group * 4;
    #pragma unroll
    for (int i2 = 0; i2 < 4; i2++) {
        int r2 = row0 + i2;
        if (r2 < N) {
            if (mode == 0) {
                float dr = dinv[r2];
                #pragma unroll
                for (int nt = 0; nt < 2; nt++) {
                    int col = wave * 32 + nt * 16 + lg;
                    float val = fmaxf(acc2[nt][i2] + bcol[nt], 0.0f);
                    __builtin_nontemporal_store(f2bf(val * dr), hout + (size_t)r2 * D + col);
                }
            } else {
                #pragma unroll
                for (int nt = 0; nt < 2; nt++) {
                    int col = wave * 32 + nt * 16 + lg;
                    __builtin_nontemporal_store(fmaxf(acc2[nt][i2] + bcol[nt], 0.0f),
                                                hrelu + (size_t)r2 * D + col);
                }
            }
        }
    }
}

// ---- segmented pooling, 4-way row-split per graph for latency hiding ----
__global__ __launch_bounds__(256) void k_pool(const float* __restrict__ hrelu,
                                              const int* __restrict__ gstart,
                                              const int* __restrict__ gcnt,
                                              float* __restrict__ pmax,
                                              float* __restrict__ psum, int B) {
    int g = blockIdx.x >> 2;
    int q = blockIdx.x & 3;
    int c = threadIdx.x & 127;
    int p = threadIdx.x >> 7;
    int start = gstart[g];
    int endr = start + gcnt[g];

    float mx0 = 0.f, mx1 = 0.f, sm0 = 0.f, sm1 = 0.f;
    int r = start + q * 2 + p;
    for (; r + 8 < endr; r += 16) {
        float v0 = __builtin_nontemporal_load(hrelu + (size_t)r * D + c);
        float v1 = __builtin_nontemporal_load(hrelu + (size_t)(r + 8) * D + c);
        mx0 = fmaxf(mx0, v0); sm0 += v0;
        mx1 = fmaxf(mx1, v1); sm1 += v1;
    }
    if (r < endr) {
        float v0 = __builtin_nontemporal_load(hrelu + (size_t)r * D + c);
        mx0 = fmaxf(mx0, v0); sm0 += v0;
    }
    float mx = fmaxf(mx0, mx1), sm = sm0 + sm1;

    __shared__ float smx[128], ssm[128];
    if (p == 1) { smx[c] = mx; ssm[c] = sm; }
    __syncthreads();
    if (p == 0) {
        pmax[((size_t)q * B + g) * D + c] = fmaxf(mx, smx[c]);
        psum[((size_t)q * B + g) * D + c] = sm + ssm[c];
    }
}

// ---- final: combine 4 partials; out[g] = [gmax, gsum/cnt, gsum] @ out_w + out_b ----
__global__ void k_final(const float* __restrict__ pmax, const float* __restrict__ psum,
                        const int* __restrict__ gcnt, const float* __restrict__ ow,
                        const float* __restrict__ ob, float* __restrict__ out, int B) {
    int g = blockIdx.x;
    int t = threadIdx.x;  // 64
    float part[10];
    #pragma unroll
    for (int o = 0; o < 10; o++) part[o] = 0.f;
    float invc = 1.0f / fmaxf((float)gcnt[g], 1.0f);
    for (int k = t; k < 3 * D; k += 64) {
        int c = (k < D) ? k : ((k < 2 * D) ? k - D : k - 2 * D);
        float pk;
        if (k < D) {
            float m = pmax[(size_t)g * D + c];
            #pragma unroll
            for (int q = 1; q < 4; q++) m = fmaxf(m, pmax[((size_t)q * B + g) * D + c]);
            pk = m;
        } else {
            float s = psum[(size_t)g * D + c];
            #pragma unroll
            for (int q = 1; q < 4; q++) s += psum[((size_t)q * B + g) * D + c];
            pk = (k < 2 * D) ? s * invc : s;
        }
        const float* w = ow + k * 10;
        #pragma unroll
        for (int o = 0; o < 10; o++) part[o] += pk * w[o];
    }
    #pragma unroll
    for (int off = 32; off > 0; off >>= 1)
        #pragma unroll
        for (int o = 0; o < 10; o++) part[o] += __shfl_down(part[o], off, 64);
    if (t == 0)
        #pragma unroll
        for (int o = 0; o < 10; o++) out[g * 10 + o] = part[o] + ob[o];
}

extern "C" void kernel_launch(void* const* d_in, const int* in_sizes, int n_in,
                              void* d_out, int out_size, void* d_ws, size_t ws_size,
                              hipStream_t stream) {
    const float* x     = (const float*)d_in[0];
    const int*   ei    = (const int*)d_in[1];
    const int*   batch = (const int*)d_in[2];
    const float* convw = (const float*)d_in[3];
    const float* convb = (const float*)d_in[4];
    const float* outw  = (const float*)d_in[5];
    const float* outb  = (const float*)d_in[6];
    float* out = (float*)d_out;

    const int N = in_sizes[0] / D;        // 100000
    const int E = in_sizes[1] / 2;        // 1600000
    const int L = in_sizes[3] / (D * D);  // 3
    const int B = out_size / 10;          // 256

    const int* src = ei;
    const int* dst = ei + E;

    const int KBE   = (N + DPB - 1) / DPB;     // coarse buckets (1563)
    const int nkeys = KBE * KPB;               // global fine-key space

    char* p = (char*)d_ws;
    auto alloc = [&](size_t bytes) { char* r = p; p += (bytes + 255) & ~255ull; return r; };
    short* hb0     = (short*)alloc((size_t)N * D * 2);      // ping-pong bf16 rows
    short* hb1     = (short*)alloc((size_t)N * D * 2);
    float* hrelu   = (float*)alloc((size_t)N * D * 4);      // fp32 last-layer relu; ALIASED as staging
    short* Wt      = (short*)alloc((size_t)L * D * D * 2);  // bf16 W^T
    int*   row_ptr = (int*)alloc(((size_t)nkeys + 1) * 4);
    int*   csr_src = (int*)alloc((size_t)E * 4);
    int*   bcnt    = (int*)alloc((size_t)SUB * KBE * 4);
    int*   btot    = (int*)alloc((size_t)KBE * 4);
    int*   bbase   = (int*)alloc(((size_t)KBE + 1) * 4);
    float* dinv    = (float*)alloc((size_t)N * 4);
    float* pmax    = (float*)alloc((size_t)4 * B * D * 4);
    float* psum    = (float*)alloc((size_t)4 * B * D * 4);
    int*   gcnt    = (int*)alloc((size_t)B * 4);
    int*   gstart  = (int*)alloc(((size_t)B + 1) * 4);

    // staging: SUB*KBE*CAP_SUB*4 = 64*1563*64*4 = 25.6 MB <= hrelu's 51.2 MB
    int* staging = (int*)hrelu;   // hrelu written only after k_build completes

    hipMemsetAsync(bcnt, 0, (size_t)SUB * KBE * 4, stream);

    k_bucket<<<(E + 255) / 256, 256, 0, stream>>>(src, dst, bcnt, staging, E, KBE);
    k_gseg<<<1, 512, 0, stream>>>(batch, gstart, gcnt, N, B);
    k_btot<<<(KBE + 255) / 256, 256, 0, stream>>>(bcnt, btot, KBE);
    k_bscan<<<1, 512, 0, stream>>>(btot, bbase, row_ptr, nkeys, KBE);
    k_build<<<KBE, 256, 0, stream>>>(staging, bcnt, bbase, row_ptr, csr_src, dinv, N, KBE);
    k_cvt_x<<<((N * D / 4) + 255) / 256, 256, 0, stream>>>(x, dinv, hb0, N * D / 4);
    k_cvt_w<<<((L * D * D) + 255) / 256, 256, 0, stream>>>(convw, Wt, L * D * D);

    const int lblocks = (N + 15) / 16;
    // layer 0: hb0 -> hb1 ; layer 1: hb1 -> hb0 ; layer 2: hb0 -> hrelu
    k_layer<<<lblocks, 256, 0, stream>>>(hb0, row_ptr, csr_src, dinv, Wt,
                                         convb, hb1, hrelu, N, 0);
    k_layer<<<lblocks, 256, 0, stream>>>(hb1, row_ptr, csr_src, dinv, Wt + D * D,
                                         convb + D, hb0, hrelu, N, 0);
    k_layer<<<lblocks, 256, 0, stream>>>(hb0, row_ptr, csr_src, dinv, Wt + 2 * D * D,
                                         convb + 2 * D, hb1, hrelu, N, 1);

    k_pool<<<B * 4, 256, 0, stream>>>(hrelu, gstart, gcnt, pmax, psum, B);
    k_final<<<B, 64, 0, stream>>>(pmax, psum, gcnt, outw, outb, out, B);
}

// Round 9
// 468.159 us; speedup vs baseline: 1.2049x; 1.0352x over previous
//
#include <hip/hip_runtime.h>
#include <hip/hip_bf16.h>

#define D 128
#define NP 8           // src-range sub-buckets per dst (csr slice order)
#define DPB 64         // dst per coarse bucket (b = d>>6)
#define KPB (DPB * NP) // fine keys per bucket = 512
#define SUB 64         // sub-cursors per bucket
#define CAP_SUB 64     // staging capacity per (sub, bucket); mean 16

typedef __attribute__((ext_vector_type(8))) __bf16 bf16x8;
typedef __attribute__((ext_vector_type(4))) float f32x4;
typedef __attribute__((ext_vector_type(4))) short s16x4;
typedef __attribute__((ext_vector_type(8))) short s16x8;

static __device__ __forceinline__ short f2bf(float f) {
    union { float f; unsigned u; } in; in.f = f;
    unsigned u = in.u;
    u += 0x7fffu + ((u >> 16) & 1u);   // round-to-nearest-even
    return (short)(u >> 16);
}

// ---- phase 1: coarse-bucket edges; 100K sub-cursors kill contention ----
// pack: fineKey(9b: (d&63)*8 + (src>>14)) << 17 | src(17b)   [N < 2^17]
// NT LOADS on src/dst (single-use streams). Staging store is a PLAIN store:
// r8 proved NT-storing the scattered staging words write-throughs 64B lines
// (WRITE_SIZE 109MB, +30us); plain stores let L2 merge within the 400KB
// per-j window before write-back.
__global__ void k_bucket(const int* __restrict__ src, const int* __restrict__ dst,
                         int* __restrict__ bcnt, int* __restrict__ staging,
                         int E, int KBE) {
    int i = blockIdx.x * 256 + threadIdx.x;
    if (i >= E) return;
    int d = __builtin_nontemporal_load(dst + i);
    int s = __builtin_nontemporal_load(src + i);
    int b = d >> 6;
    int key = ((d & 63) << 3) | (s >> 14);
    int j = blockIdx.x & (SUB - 1);      // j%8 == heuristic XCD
    int slot = atomicAdd(&bcnt[j * KBE + b], 1);
    if (slot < CAP_SUB) staging[((size_t)j * KBE + b) * CAP_SUB + slot] = (key << 17) | s;
}

// ---- per-bucket totals (parallel, coalesced per-j stripes) ----
__global__ void k_btot(const int* __restrict__ bcnt, int* __restrict__ btot, int KBE) {
    int b = blockIdx.x * 256 + threadIdx.x;
    if (b >= KBE) return;
    int v = 0;
    #pragma unroll
    for (int j = 0; j < SUB; j++) {
        int c = bcnt[j * KBE + b];
        v += (c > CAP_SUB) ? CAP_SUB : c;
    }
    btot[b] = v;
}

// ---- exclusive scan of bucket totals (single block, chunked) ----
__global__ void k_bscan(const int* __restrict__ btot, int* __restrict__ bbase,
                        int* __restrict__ row_ptr, int nkeys, int KBE) {
    __shared__ int sm[512];
    __shared__ int carry;
    int t = threadIdx.x;
    if (t == 0) carry = 0;
    __syncthreads();
    for (int c0 = 0; c0 < KBE; c0 += 512) {
        int b = c0 + t;
        int v = (b < KBE) ? btot[b] : 0;
        sm[t] = v;
        __syncthreads();
        for (int off = 1; off < 512; off <<= 1) {
            int x = (t >= off) ? sm[t - off] : 0;
            __syncthreads();
            sm[t] += x;
            __syncthreads();
        }
        if (b < KBE) bbase[b] = sm[t] - v + carry;
        __syncthreads();
        if (t == 0) carry += sm[511];
        __syncthreads();
    }
    if (t == 0) { bbase[KBE] = carry; row_ptr[nkeys] = carry; }
}

// ---- phase 2: per-bucket fine CSR build in LDS; no binary search, no serial prefix ----
// thread t owns lane (t&3) of sub-region j = t>>2  (4 threads per sub, ~16 edges each)
__global__ __launch_bounds__(256) void k_build(
    const int* __restrict__ staging, const int* __restrict__ bcnt,
    const int* __restrict__ bbase, int* __restrict__ row_ptr,
    int* __restrict__ csr_src, float* __restrict__ dinv, int N, int KBE)
{
    const int b = blockIdx.x;
    const int tid = threadIdx.x;
    __shared__ int cnt[KPB];
    __shared__ int subn[SUB];
    __shared__ int chunkbuf[256];
    __shared__ int carry;

    if (tid < SUB) {
        int c = bcnt[tid * KBE + b];
        subn[tid] = (c > CAP_SUB) ? CAP_SUB : c;
    }
    for (int k = tid; k < KPB; k += 256) cnt[k] = 0;
    if (tid == 0) carry = 0;
    __syncthreads();

    const int base = bbase[b];
    const int nb = bbase[b + 1] - base;          // bucket total (from scan)
    const int j = tid >> 2, l4 = tid & 3;
    const int* __restrict__ sreg = staging + ((size_t)j * KBE + b) * CAP_SUB;
    const int sn = subn[j];

    // histogram over fine keys
    for (int e = l4; e < sn; e += 4)
        atomicAdd(&cnt[sreg[e] >> 17], 1);
    __syncthreads();

    // in-place exclusive scan of cnt[0..KPB)  (2 chunks of 256)
    #pragma unroll 1
    for (int c = 0; c < KPB / 256; c++) {
        int idx = c * 256 + tid;
        int v = cnt[idx];
        chunkbuf[tid] = v;
        __syncthreads();
        for (int off = 1; off < 256; off <<= 1) {
            int x = (tid >= off) ? chunkbuf[tid - off] : 0;
            __syncthreads();
            chunkbuf[tid] += x;
            __syncthreads();
        }
        cnt[idx] = chunkbuf[tid] - v + carry;
        __syncthreads();
        if (tid == 255) carry += chunkbuf[255];
        __syncthreads();
    }

    for (int k = tid; k < KPB; k += 256)
        row_ptr[(size_t)b * KPB + k] = base + cnt[k];
    for (int dl = tid; dl < DPB; dl += 256) {
        int d = b * DPB + dl;
        if (d < N) {
            int hi2 = (dl == DPB - 1) ? nb : cnt[(dl + 1) * NP];
            int deg = hi2 - cnt[dl * NP];
            dinv[d] = rsqrtf((float)deg + 1.0f);
        }
    }
    __syncthreads();

    // scatter into this bucket's contiguous csr region (LDS cursors)
    for (int e = l4; e < sn; e += 4) {
        int w = sreg[e];
        int slot = base + atomicAdd(&cnt[w >> 17], 1);
        csr_src[slot] = w & 0x1FFFF;
    }
}

// ---- batch is SORTED: segment starts AND counts via binary search ----
__global__ void k_gseg(const int* __restrict__ batch, int* __restrict__ gstart,
                       int* __restrict__ gcnt, int N, int B) {
    int g = blockIdx.x * blockDim.x + threadIdx.x;
    if (g > B) return;
    int lo = 0, hi = N;
    while (lo < hi) {
        int mid = (lo + hi) >> 1;
        if (batch[mid] < g) lo = mid + 1; else hi = mid;
    }
    gstart[g] = lo;
    if (g < B) {
        int lo2 = lo, hi2 = N;
        while (lo2 < hi2) {
            int mid = (lo2 + hi2) >> 1;
            if (batch[mid] < g + 1) lo2 = mid + 1; else hi2 = mid;
        }
        gcnt[g] = lo2 - lo;
    }
}

// ---- x' = dinv[i] * x  -> bf16 (pre-scaled feature rows) ----
__global__ void k_cvt_x(const float* __restrict__ x, const float* __restrict__ dinv,
                        short* __restrict__ xb, int total4) {
    int i = blockIdx.x * blockDim.x + threadIdx.x;
    if (i < total4) {
        float d = dinv[i >> 5];
        f32x4 v = __builtin_nontemporal_load((const f32x4*)x + i);
        s16x4 o;
        o.x = f2bf(v.x * d); o.y = f2bf(v.y * d);
        o.z = f2bf(v.z * d); o.w = f2bf(v.w * d);
        ((s16x4*)xb)[i] = o;
    }
}

// ---- conv_w: fp32 [L][k][n] -> bf16 transposed [L][n][k] ----
__global__ void k_cvt_w(const float* __restrict__ W, short* __restrict__ Wt, int total) {
    int i = blockIdx.x * blockDim.x + threadIdx.x;
    if (i < total) {
        int l = i >> 14;
        int rem = i & 16383;
        int n = rem >> 7;
        int k = rem & 127;
        Wt[i] = f2bf(W[(l << 14) + (k << 7) + n]);
    }
}

// ---- FUSED layer (r3 structure + NT LOADS only on csr/row_ptr) ----
// 16 nodes/block, 8-deep pipelined gather chains, 1 barrier, 16x128 MFMA GEMM.
// NT loads keep the 6.4MB csr stream out of L2 (hin residency). Stores are
// PLAIN (r8: NT stores bypass L2/LLC -> next layer's gathers start cold).
// mode 0: hout[r] = bf16( relu(C + b) * dinv[r] );  mode 1: hrelu[r] = fp32 relu(C+b)
__global__ __launch_bounds__(256) void k_layer(
    const short* __restrict__ hin, const int* __restrict__ row_ptr,
    const int* __restrict__ csr_src, const float* __restrict__ dinv,
    const short* __restrict__ Wt, const float* __restrict__ bias,
    short* __restrict__ hout, float* __restrict__ hrelu, int N, int mode)
{
    __shared__ __align__(16) short tile[16 * 128];   // 4 KB, swizzled 16B chunks
    const int tid = threadIdx.x;
    const int wave = tid >> 6;
    const int lane = tid & 63;
    const int group = lane >> 4;
    const int lg = lane & 15;
    const int off = lg * 8;
    const int node_base = blockIdx.x * 16;
    const int r = wave * 4 + group;          // tile row this group owns (0..15)
    const int i = node_base + r;

    // ---- phase 1: aggregate one node per group (16 concurrent per block) ----
    short* dstp = &tile[r * 128 + ((lg ^ (r & 7)) << 3)];
    if (i < N) {
        float acc[8];
        bf16x8 v = *(const bf16x8*)(hin + (size_t)i * D + off);
        #pragma unroll
        for (int k = 0; k < 8; k++) acc[k] = (float)v[k];

        int t = __builtin_nontemporal_load(row_ptr + i * NP);
        const int end = __builtin_nontemporal_load(row_ptr + i * NP + NP);
        const int nfull = (end - t) >> 3;    // full 8-chains

        int i0, i1, i2, i3, i4, i5, i6, i7;
        if (nfull > 0) {
            i0 = __builtin_nontemporal_load(csr_src + t + 0);
            i1 = __builtin_nontemporal_load(csr_src + t + 1);
            i2 = __builtin_nontemporal_load(csr_src + t + 2);
            i3 = __builtin_nontemporal_load(csr_src + t + 3);
            i4 = __builtin_nontemporal_load(csr_src + t + 4);
            i5 = __builtin_nontemporal_load(csr_src + t + 5);
            i6 = __builtin_nontemporal_load(csr_src + t + 6);
            i7 = __builtin_nontemporal_load(csr_src + t + 7);
        }
        #pragma unroll 1
        for (int c = 0; c < nfull; c++) {
            bf16x8 v0 = *(const bf16x8*)(hin + (size_t)i0 * D + off);
            bf16x8 v1 = *(const bf16x8*)(hin + (size_t)i1 * D + off);
            bf16x8 v2 = *(const bf16x8*)(hin + (size_t)i2 * D + off);
            bf16x8 v3 = *(const bf16x8*)(hin + (size_t)i3 * D + off);
            bf16x8 v4 = *(const bf16x8*)(hin + (size_t)i4 * D + off);
            bf16x8 v5 = *(const bf16x8*)(hin + (size_t)i5 * D + off);
            bf16x8 v6 = *(const bf16x8*)(hin + (size_t)i6 * D + off);
            bf16x8 v7 = *(const bf16x8*)(hin + (size_t)i7 * D + off);
            t += 8;
            if (c + 1 < nfull) {             // prefetch next indices while rows fly
                i0 = __builtin_nontemporal_load(csr_src + t + 0);
                i1 = __builtin_nontemporal_load(csr_src + t + 1);
                i2 = __builtin_nontemporal_load(csr_src + t + 2);
                i3 = __builtin_nontemporal_load(csr_src + t + 3);
                i4 = __builtin_nontemporal_load(csr_src + t + 4);
                i5 = __builtin_nontemporal_load(csr_src + t + 5);
                i6 = __builtin_nontemporal_load(csr_src + t + 6);
                i7 = __builtin_nontemporal_load(csr_src + t + 7);
            }
            #pragma unroll
            for (int k = 0; k < 8; k++)
                acc[k] += ((((float)v0[k] + (float)v1[k]) + ((float)v2[k] + (float)v3[k]))
                         + (((float)v4[k] + (float)v5[k]) + ((float)v6[k] + (float)v7[k])));
        }
        for (; t + 4 <= end; t += 4) {       // 4-deep tail
            int j0 = __builtin_nontemporal_load(csr_src + t + 0);
            int j1 = __builtin_nontemporal_load(csr_src + t + 1);
            int j2 = __builtin_nontemporal_load(csr_src + t + 2);
            int j3 = __builtin_nontemporal_load(csr_src + t + 3);
            bf16x8 v0 = *(const bf16x8*)(hin + (size_t)j0 * D + off);
            bf16x8 v1 = *(const bf16x8*)(hin + (size_t)j1 * D + off);
            bf16x8 v2 = *(const bf16x8*)(hin + (size_t)j2 * D + off);
            bf16x8 v3 = *(const bf16x8*)(hin + (size_t)j3 * D + off);
            #pragma unroll
            for (int k = 0; k < 8; k++)
                acc[k] += (((float)v0[k] + (float)v1[k]) + ((float)v2[k] + (float)v3[k]));
        }
        for (; t < end; t++) {               // scalar tail (<=3)
            int j0 = __builtin_nontemporal_load(csr_src + t);
            bf16x8 v0 = *(const bf16x8*)(hin + (size_t)j0 * D + off);
            #pragma unroll
            for (int k = 0; k < 8; k++) acc[k] += (float)v0[k];
        }

        const float di = dinv[i];
        s16x8 o;
        #pragma unroll
        for (int k = 0; k < 8; k++) o[k] = f2bf(acc[k] * di);
        *(s16x8*)dstp = o;
    } else {
        s16x8 z = {0, 0, 0, 0, 0, 0, 0, 0};
        *(s16x8*)dstp = z;
    }
    __syncthreads();

    // ---- phase 2: cooperative GEMM; wave w computes cols [w*32, w*32+32) ----
    bf16x8 afrag[4];
    #pragma unroll
    for (int kt = 0; kt < 4; kt++)
        afrag[kt] = *(const bf16x8*)(&tile[lg * 128 + (((group + 4 * kt) ^ (lg & 7)) << 3)]);

    f32x4 acc2[2];
    #pragma unroll
    for (int nt = 0; nt < 2; nt++) { f32x4 z = {0.f, 0.f, 0.f, 0.f}; acc2[nt] = z; }
    #pragma unroll
    for (int nt = 0; nt < 2; nt++) {
        const short* bp = Wt + (size_t)(wave * 32 + nt * 16 + lg) * D + group * 8;
        #pragma unroll
        for (int kt = 0; kt < 4; kt++) {
            bf16x8 b = *(const bf16x8*)(bp + kt * 32);
            acc2[nt] = __builtin_amdgcn_mfma_f32_16x16x32_bf16(afrag[kt], b, acc2[nt], 0, 0, 0);
        }
    }

    // C/D layout: col = lane&15, row = (lane>>4)*4 + reg
    float bcol[2];
    #pragma unroll
    for (int nt = 0; nt < 2; nt++) bcol[nt] = bias[wave * 32 + nt * 16 + lg];
    const int row0 = node_base + group * 4;
    #pragma unroll
    for (int i2 = 0; i2 < 4; i2++) {
        int r2 = row0 + i2;
        if (r2 < N) {
            if (mode == 0) {
                float dr = dinv[r2];
                #pragma unroll
                for (int nt = 0; nt < 2; nt++) {
                    int col = wave * 32 + nt * 16 + lg;
                    float val = fmaxf(acc2[nt][i2] + bcol[nt], 0.0f);
                    hout[(size_t)r2 * D + col] = f2bf(val * dr);
                }
            } else {
                #pragma unroll
                for (int nt = 0; nt < 2; nt++) {
                    int col = wave * 32 + nt * 16 + lg;
                    hrelu[(size_t)r2 * D + col] = fmaxf(acc2[nt][i2] + bcol[nt], 0.0f);
                }
            }
        }
    }
}

// ---- segmented pooling, 4-way row-split per graph for latency hiding ----
__global__ __launch_bounds__(256) void k_pool(const float* __restrict__ hrelu,
                                              const int* __restrict__ gstart,
                                              const int* __restrict__ gcnt,
                                              float* __restrict__ pmax,
                                              float* __restrict__ psum, int B) {
    int g = blockIdx.x >> 2;
    int q = blockIdx.x & 3;
    int c = threadIdx.x & 127;
    int p = threadIdx.x >> 7;
    int start = gstart[g];
    int endr = start + gcnt[g];

    float mx0 = 0.f, mx1 = 0.f, sm0 = 0.f, sm1 = 0.f;
    int r = start + q * 2 + p;
    for (; r + 8 < endr; r += 16) {
        float v0 = __builtin_nontemporal_load(hrelu + (size_t)r * D + c);
        float v1 = __builtin_nontemporal_load(hrelu + (size_t)(r + 8) * D + c);
        mx0 = fmaxf(mx0, v0); sm0 += v0;
        mx1 = fmaxf(mx1, v1); sm1 += v1;
    }
    if (r < endr) {
        float v0 = __builtin_nontemporal_load(hrelu + (size_t)r * D + c);
        mx0 = fmaxf(mx0, v0); sm0 += v0;
    }
    float mx = fmaxf(mx0, mx1), sm = sm0 + sm1;

    __shared__ float smx[128], ssm[128];
    if (p == 1) { smx[c] = mx; ssm[c] = sm; }
    __syncthreads();
    if (p == 0) {
        pmax[((size_t)q * B + g) * D + c] = fmaxf(mx, smx[c]);
        psum[((size_t)q * B + g) * D + c] = sm + ssm[c];
    }
}

// ---- final: combine 4 partials; out[g] = [gmax, gsum/cnt, gsum] @ out_w + out_b ----
__global__ void k_final(const float* __restrict__ pmax, const float* __restrict__ psum,
                        const int* __restrict__ gcnt, const float* __restrict__ ow,
                        const float* __restrict__ ob, float* __restrict__ out, int B) {
    int g = blockIdx.x;
    int t = threadIdx.x;  // 64
    float part[10];
    #pragma unroll
    for (int o = 0; o < 10; o++) part[o] = 0.f;
    float invc = 1.0f / fmaxf((float)gcnt[g], 1.0f);
    for (int k = t; k < 3 * D; k += 64) {
        int c = (k < D) ? k : ((k < 2 * D) ? k - D : k - 2 * D);
        float pk;
        if (k < D) {
            float m = pmax[(size_t)g * D + c];
            #pragma unroll
            for (int q = 1; q < 4; q++) m = fmaxf(m, pmax[((size_t)q * B + g) * D + c]);
            pk = m;
        } else {
            float s = psum[(size_t)g * D + c];
            #pragma unroll
            for (int q = 1; q < 4; q++) s += psum[((size_t)q * B + g) * D + c];
            pk = (k < 2 * D) ? s * invc : s;
        }
        const float* w = ow + k * 10;
        #pragma unroll
        for (int o = 0; o < 10; o++) part[o] += pk * w[o];
    }
    #pragma unroll
    for (int off = 32; off > 0; off >>= 1)
        #pragma unroll
        for (int o = 0; o < 10; o++) part[o] += __shfl_down(part[o], off, 64);
    if (t == 0)
        #pragma unroll
        for (int o = 0; o < 10; o++) out[g * 10 + o] = part[o] + ob[o];
}

extern "C" void kernel_launch(void* const* d_in, const int* in_sizes, int n_in,
                              void* d_out, int out_size, void* d_ws, size_t ws_size,
                              hipStream_t stream) {
    const float* x     = (const float*)d_in[0];
    const int*   ei    = (const int*)d_in[1];
    const int*   batch = (const int*)d_in[2];
    const float* convw = (const float*)d_in[3];
    const float* convb = (const float*)d_in[4];
    const float* outw  = (const float*)d_in[5];
    const float* outb  = (const float*)d_in[6];
    float* out = (float*)d_out;

    const int N = in_sizes[0] / D;        // 100000
    const int E = in_sizes[1] / 2;        // 1600000
    const int L = in_sizes[3] / (D * D);  // 3
    const int B = out_size / 10;          // 256

    const int* src = ei;
    const int* dst = ei + E;

    const int KBE   = (N + DPB - 1) / DPB;     // coarse buckets (1563)
    const int nkeys = KBE * KPB;               // global fine-key space

    char* p = (char*)d_ws;
    auto alloc = [&](size_t bytes) { char* r = p; p += (bytes + 255) & ~255ull; return r; };
    short* hb0     = (short*)alloc((size_t)N * D * 2);      // ping-pong bf16 rows
    short* hb1     = (short*)alloc((size_t)N * D * 2);
    float* hrelu   = (float*)alloc((size_t)N * D * 4);      // fp32 last-layer relu; ALIASED as staging
    short* Wt      = (short*)alloc((size_t)L * D * D * 2);  // bf16 W^T
    int*   row_ptr = (int*)alloc(((size_t)nkeys + 1) * 4);
    int*   csr_src = (int*)alloc((size_t)E * 4);
    int*   bcnt    = (int*)alloc((size_t)SUB * KBE * 4);
    int*   btot    = (int*)alloc((size_t)KBE * 4);
    int*   bbase   = (int*)alloc(((size_t)KBE + 1) * 4);
    float* dinv    = (float*)alloc((size_t)N * 4);
    float* pmax    = (float*)alloc((size_t)4 * B * D * 4);
    float* psum    = (float*)alloc((size_t)4 * B * D * 4);
    int*   gcnt    = (int*)alloc((size_t)B * 4);
    int*   gstart  = (int*)alloc(((size_t)B + 1) * 4);

    // staging: SUB*KBE*CAP_SUB*4 = 64*1563*64*4 = 25.6 MB <= hrelu's 51.2 MB
    int* staging = (int*)hrelu;   // hrelu written only after k_build completes

    hipMemsetAsync(bcnt, 0, (size_t)SUB * KBE * 4, stream);

    k_bucket<<<(E + 255) / 256, 256, 0, stream>>>(src, dst, bcnt, staging, E, KBE);
    k_gseg<<<1, 512, 0, stream>>>(batch, gstart, gcnt, N, B);
    k_btot<<<(KBE + 255) / 256, 256, 0, stream>>>(bcnt, btot, KBE);
    k_bscan<<<1, 512, 0, stream>>>(btot, bbase, row_ptr, nkeys, KBE);
    k_build<<<KBE, 256, 0, stream>>>(staging, bcnt, bbase, row_ptr, csr_src, dinv, N, KBE);
    k_cvt_x<<<((N * D / 4) + 255) / 256, 256, 0, stream>>>(x, dinv, hb0, N * D / 4);
    k_cvt_w<<<((L * D * D) + 255) / 256, 256, 0, stream>>>(convw, Wt, L * D * D);

    const int lblocks = (N + 15) / 16;
    // layer 0: hb0 -> hb1 ; layer 1: hb1 -> hb0 ; layer 2: hb0 -> hrelu
    k_layer<<<lblocks, 256, 0, stream>>>(hb0, row_ptr, csr_src, dinv, Wt,
                                         convb, hb1, hrelu, N, 0);
    k_layer<<<lblocks, 256, 0, stream>>>(hb1, row_ptr, csr_src, dinv, Wt + D * D,
                                         convb + D, hb0, hrelu, N, 0);
    k_layer<<<lblocks, 256, 0, stream>>>(hb0, row_ptr, csr_src, dinv, Wt + 2 * D * D,
                                         convb + 2 * D, hb1, hrelu, N, 1);

    k_pool<<<B * 4, 256, 0, stream>>>(hrelu, gstart, gcnt, pmax, psum, B);
    k_final<<<B, 64, 0, stream>>>(pmax, psum, gcnt, outw, outb, out, B);
}

// Round 10
// 453.978 us; speedup vs baseline: 1.2425x; 1.0312x over previous
//
#include <hip/hip_runtime.h>
#include <hip/hip_bf16.h>

#define D 128
#define NP 8           // src-range sub-buckets per dst (csr slice order)
#define DPB 64         // dst per coarse bucket (b = d>>6)
#define KPB (DPB * NP) // fine keys per bucket = 512
#define SUB 64         // sub-cursors per bucket
#define CAP_SUB 64     // staging capacity per (sub, bucket); mean 16

typedef __attribute__((ext_vector_type(8))) __bf16 bf16x8;
typedef __attribute__((ext_vector_type(4))) float f32x4;
typedef __attribute__((ext_vector_type(4))) short s16x4;
typedef __attribute__((ext_vector_type(8))) short s16x8;

static __device__ __forceinline__ short f2bf(float f) {
    union { float f; unsigned u; } in; in.f = f;
    unsigned u = in.u;
    u += 0x7fffu + ((u >> 16) & 1u);   // round-to-nearest-even
    return (short)(u >> 16);
}

// ---- phase 1 (FUSED): coarse-bucket edges + cvt_w + gseg tail blocks ----
// pack: fineKey(9b: (d&63)*8 + (src>>14)) << 17 | src(17b)   [N < 2^17]
// j = blockIdx&63: same-j blocks land on the same XCD (round-robin), so each
// j's 400KB staging window stays in one L2 -> writes merge before writeback.
__global__ void k_bucket(const int* __restrict__ src, const int* __restrict__ dst,
                         int* __restrict__ bcnt, int* __restrict__ staging,
                         int E, int KBE,
                         const float* __restrict__ W, short* __restrict__ Wt, int totw,
                         const int* __restrict__ batch, int* __restrict__ gstart,
                         int* __restrict__ gcnt, int N, int B) {
    const int EB = (E + 255) >> 8;
    if (blockIdx.x < (unsigned)EB) {
        int i = blockIdx.x * 256 + threadIdx.x;
        if (i >= E) return;
        int d = __builtin_nontemporal_load(dst + i);
        int s = __builtin_nontemporal_load(src + i);
        int b = d >> 6;
        int key = ((d & 63) << 3) | (s >> 14);
        int j = blockIdx.x & (SUB - 1);      // j%8 == heuristic XCD
        int slot = atomicAdd(&bcnt[j * KBE + b], 1);
        if (slot < CAP_SUB) staging[((size_t)j * KBE + b) * CAP_SUB + slot] = (key << 17) | s;
    } else if ((int)blockIdx.x - EB < (totw >> 8)) {
        // conv_w: fp32 [L][k][n] -> bf16 transposed [L][n][k]
        int i = (blockIdx.x - EB) * 256 + threadIdx.x;
        if (i < totw) {
            int l = i >> 14;
            int rem = i & 16383;
            int n = rem >> 7;
            int k = rem & 127;
            Wt[i] = f2bf(W[(l << 14) + (k << 7) + n]);
        }
    } else {
        // batch is SORTED: segment starts AND counts via binary search
        for (int g = threadIdx.x; g <= B; g += 256) {
            int lo = 0, hi = N;
            while (lo < hi) {
                int mid = (lo + hi) >> 1;
                if (batch[mid] < g) lo = mid + 1; else hi = mid;
            }
            gstart[g] = lo;
            if (g < B) {
                int lo2 = lo, hi2 = N;
                while (lo2 < hi2) {
                    int mid = (lo2 + hi2) >> 1;
                    if (batch[mid] < g + 1) lo2 = mid + 1; else hi2 = mid;
                }
                gcnt[g] = lo2 - lo;
            }
        }
    }
}

// ---- fused btot + exclusive scan of bucket totals (single block, shuffle scan) ----
__global__ void k_bscan(const int* __restrict__ bcnt, int* __restrict__ bbase,
                        int* __restrict__ row_ptr, int nkeys, int KBE) {
    __shared__ int wtot[8];
    __shared__ int carry_s;
    const int t = threadIdx.x;
    const int w = t >> 6;
    const int lane = t & 63;
    if (t == 0) carry_s = 0;
    __syncthreads();
    for (int c0 = 0; c0 < KBE; c0 += 512) {
        const int b = c0 + t;
        int v = 0;
        if (b < KBE) {
            #pragma unroll 8
            for (int j = 0; j < SUB; j++) {      // coalesced per-j stripes
                int c = bcnt[j * KBE + b];
                v += (c > CAP_SUB) ? CAP_SUB : c;
            }
        }
        int is = v;                               // wave inclusive scan
        #pragma unroll
        for (int off = 1; off < 64; off <<= 1) {
            int x = __shfl_up(is, off, 64);
            if (lane >= off) is += x;
        }
        if (lane == 63) wtot[w] = is;
        __syncthreads();
        if (t == 0) {
            int run = 0;
            #pragma unroll
            for (int i = 0; i < 8; i++) { int x = wtot[i]; wtot[i] = run; run += x; }
        }
        __syncthreads();
        const int excl = is - v + wtot[w] + carry_s;
        if (b < KBE) bbase[b] = excl;
        __syncthreads();                          // everyone read carry_s
        if (t == 511) carry_s = excl + v;         // chunk total folded in
        __syncthreads();
    }
    if (t == 0) { bbase[KBE] = carry_s; row_ptr[nkeys] = carry_s; }
}

// ---- phase 2: per-bucket fine CSR build in LDS; shuffle-scan (3 barriers) ----
// thread t owns lane (t&3) of sub-region j = t>>2  (4 threads per sub, ~16 edges each)
__global__ __launch_bounds__(256) void k_build(
    const int* __restrict__ staging, const int* __restrict__ bcnt,
    const int* __restrict__ bbase, int* __restrict__ row_ptr,
    int* __restrict__ csr_src, float* __restrict__ dinv, int N, int KBE)
{
    const int b = blockIdx.x;
    const int tid = threadIdx.x;
    __shared__ int cnt[KPB];
    __shared__ int subn[SUB];
    __shared__ int wtot[4];

    if (tid < SUB) {
        int c = bcnt[tid * KBE + b];
        subn[tid] = (c > CAP_SUB) ? CAP_SUB : c;
    }
    for (int k = tid; k < KPB; k += 256) cnt[k] = 0;
    __syncthreads();

    const int base = bbase[b];
    const int nb = bbase[b + 1] - base;          // bucket total (from scan)
    const int j = tid >> 2, l4 = tid & 3;
    const int* __restrict__ sreg = staging + ((size_t)j * KBE + b) * CAP_SUB;
    const int sn = subn[j];

    // histogram over fine keys
    for (int e = l4; e < sn; e += 4)
        atomicAdd(&cnt[sreg[e] >> 17], 1);
    __syncthreads();

    // exclusive scan of cnt[0..512): 2 elems/thread, wave shuffle scan
    {
        const int w = tid >> 6, lane = tid & 63;
        const int e0 = cnt[2 * tid], e1 = cnt[2 * tid + 1];
        const int s = e0 + e1;
        int is = s;
        #pragma unroll
        for (int off = 1; off < 64; off <<= 1) {
            int x = __shfl_up(is, off, 64);
            if (lane >= off) is += x;
        }
        if (lane == 63) wtot[w] = is;
        __syncthreads();
        if (tid == 0) {
            int run = 0;
            #pragma unroll
            for (int i = 0; i < 4; i++) { int x = wtot[i]; wtot[i] = run; run += x; }
        }
        __syncthreads();
        const int excl = is - s + wtot[w];
        cnt[2 * tid] = excl;
        cnt[2 * tid + 1] = excl + e0;
        __syncthreads();
    }

    for (int k = tid; k < KPB; k += 256)
        row_ptr[(size_t)b * KPB + k] = base + cnt[k];
    for (int dl = tid; dl < DPB; dl += 256) {
        int d = b * DPB + dl;
        if (d < N) {
            int hi2 = (dl == DPB - 1) ? nb : cnt[(dl + 1) * NP];
            int deg = hi2 - cnt[dl * NP];
            dinv[d] = rsqrtf((float)deg + 1.0f);
        }
    }
    __syncthreads();

    // scatter into this bucket's contiguous csr region (LDS cursors)
    for (int e = l4; e < sn; e += 4) {
        int w = sreg[e];
        int slot = base + atomicAdd(&cnt[w >> 17], 1);
        csr_src[slot] = w & 0x1FFFF;
    }
}

// ---- x' = dinv[i] * x  -> bf16 (pre-scaled feature rows) ----
__global__ void k_cvt_x(const float* __restrict__ x, const float* __restrict__ dinv,
                        short* __restrict__ xb, int total4) {
    int i = blockIdx.x * blockDim.x + threadIdx.x;
    if (i < total4) {
        float d = dinv[i >> 5];
        f32x4 v = __builtin_nontemporal_load((const f32x4*)x + i);
        s16x4 o;
        o.x = f2bf(v.x * d); o.y = f2bf(v.y * d);
        o.z = f2bf(v.z * d); o.w = f2bf(v.w * d);
        ((s16x4*)xb)[i] = o;
    }
}

// ---- FUSED layer (r3-exact: plain loads; proven 83.7us floor) ----
// 16 nodes/block, 8-deep pipelined gather chains, 1 barrier, 16x128 MFMA GEMM.
// Floor established over 8 variants (r0-r9): random-gather line-rate limit.
// NT hints on csr/row_ptr REVERTED (r9: +4us/layer, FETCH +10MB — csr lines
// serve 2 chains, NT kills the second touch).
// mode 0: hout[r] = bf16( relu(C + b) * dinv[r] );  mode 1: hrelu[r] = fp32 relu(C+b)
__global__ __launch_bounds__(256) void k_layer(
    const short* __restrict__ hin, const int* __restrict__ row_ptr,
    const int* __restrict__ csr_src, const float* __restrict__ dinv,
    const short* __restrict__ Wt, const float* __restrict__ bias,
    short* __restrict__ hout, float* __restrict__ hrelu, int N, int mode)
{
    __shared__ __align__(16) short tile[16 * 128];   // 4 KB, swizzled 16B chunks
    const int tid = threadIdx.x;
    const int wave = tid >> 6;
    const int lane = tid & 63;
    const int group = lane >> 4;
    const int lg = lane & 15;
    const int off = lg * 8;
    const int node_base = blockIdx.x * 16;
    const int r = wave * 4 + group;          // tile row this group owns (0..15)
    const int i = node_base + r;

    // ---- phase 1: aggregate one node per group (16 concurrent per block) ----
    short* dstp = &tile[r * 128 + ((lg ^ (r & 7)) << 3)];
    if (i < N) {
        float acc[8];
        bf16x8 v = *(const bf16x8*)(hin + (size_t)i * D + off);
        #pragma unroll
        for (int k = 0; k < 8; k++) acc[k] = (float)v[k];

        int t = row_ptr[i * NP];
        const int end = row_ptr[i * NP + NP];
        const int nfull = (end - t) >> 3;    // full 8-chains

        int i0, i1, i2, i3, i4, i5, i6, i7;
        if (nfull > 0) {
            i0 = csr_src[t + 0]; i1 = csr_src[t + 1];
            i2 = csr_src[t + 2]; i3 = csr_src[t + 3];
            i4 = csr_src[t + 4]; i5 = csr_src[t + 5];
            i6 = csr_src[t + 6]; i7 = csr_src[t + 7];
        }
        #pragma unroll 1
        for (int c = 0; c < nfull; c++) {
            bf16x8 v0 = *(const bf16x8*)(hin + (size_t)i0 * D + off);
            bf16x8 v1 = *(const bf16x8*)(hin + (size_t)i1 * D + off);
            bf16x8 v2 = *(const bf16x8*)(hin + (size_t)i2 * D + off);
            bf16x8 v3 = *(const bf16x8*)(hin + (size_t)i3 * D + off);
            bf16x8 v4 = *(const bf16x8*)(hin + (size_t)i4 * D + off);
            bf16x8 v5 = *(const bf16x8*)(hin + (size_t)i5 * D + off);
            bf16x8 v6 = *(const bf16x8*)(hin + (size_t)i6 * D + off);
            bf16x8 v7 = *(const bf16x8*)(hin + (size_t)i7 * D + off);
            t += 8;
            if (c + 1 < nfull) {             // prefetch next indices while rows fly
                i0 = csr_src[t + 0]; i1 = csr_src[t + 1];
                i2 = csr_src[t + 2]; i3 = csr_src[t + 3];
                i4 = csr_src[t + 4]; i5 = csr_src[t + 5];
                i6 = csr_src[t + 6]; i7 = csr_src[t + 7];
            }
            #pragma unroll
            for (int k = 0; k < 8; k++)
                acc[k] += ((((float)v0[k] + (float)v1[k]) + ((float)v2[k] + (float)v3[k]))
                         + (((float)v4[k] + (float)v5[k]) + ((float)v6[k] + (float)v7[k])));
        }
        for (; t + 4 <= end; t += 4) {       // 4-deep tail
            int j0 = csr_src[t + 0], j1 = csr_src[t + 1];
            int j2 = csr_src[t + 2], j3 = csr_src[t + 3];
            bf16x8 v0 = *(const bf16x8*)(hin + (size_t)j0 * D + off);
            bf16x8 v1 = *(const bf16x8*)(hin + (size_t)j1 * D + off);
            bf16x8 v2 = *(const bf16x8*)(hin + (size_t)j2 * D + off);
            bf16x8 v3 = *(const bf16x8*)(hin + (size_t)j3 * D + off);
            #pragma unroll
            for (int k = 0; k < 8; k++)
                acc[k] += (((float)v0[k] + (float)v1[k]) + ((float)v2[k] + (float)v3[k]));
        }
        for (; t < end; t++) {               // scalar tail (<=3)
            int j0 = csr_src[t];
            bf16x8 v0 = *(const bf16x8*)(hin + (size_t)j0 * D + off);
            #pragma unroll
            for (int k = 0; k < 8; k++) acc[k] += (float)v0[k];
        }

        const float di = dinv[i];
        s16x8 o;
        #pragma unroll
        for (int k = 0; k < 8; k++) o[k] = f2bf(acc[k] * di);
        *(s16x8*)dstp = o;
    } else {
        s16x8 z = {0, 0, 0, 0, 0, 0, 0, 0};
        *(s16x8*)dstp = z;
    }
    __syncthreads();

    // ---- phase 2: cooperative GEMM; wave w computes cols [w*32, w*32+32) ----
    bf16x8 afrag[4];
    #pragma unroll
    for (int kt = 0; kt < 4; kt++)
        afrag[kt] = *(const bf16x8*)(&tile[lg * 128 + (((group + 4 * kt) ^ (lg & 7)) << 3)]);

    f32x4 acc2[2];
    #pragma unroll
    for (int nt = 0; nt < 2; nt++) { f32x4 z = {0.f, 0.f, 0.f, 0.f}; acc2[nt] = z; }
    #pragma unroll
    for (int nt = 0; nt < 2; nt++) {
        const short* bp = Wt + (size_t)(wave * 32 + nt * 16 + lg) * D + group * 8;
        #pragma unroll
        for (int kt = 0; kt < 4; kt++) {
            bf16x8 b = *(const bf16x8*)(bp + kt * 32);
            acc2[nt] = __builtin_amdgcn_mfma_f32_16x16x32_bf16(afrag[kt], b, acc2[nt], 0, 0, 0);
        }
    }

    // C/D layout: col = lane&15, row = (lane>>4)*4 + reg
    float bcol[2];
    #pragma unroll
    for (int nt = 0; nt < 2; nt++) bcol[nt] = bias[wave * 32 + nt * 16 + lg];
    const int row0 = node_base + group * 4;
    #pragma unroll
    for (int i2 = 0; i2 < 4; i2++) {
        int r2 = row0 + i2;
        if (r2 < N) {
            if (mode == 0) {
                float dr = dinv[r2];
                #pragma unroll
                for (int nt = 0; nt < 2; nt++) {
                    int col = wave * 32 + nt * 16 + lg;
                    float val = fmaxf(acc2[nt][i2] + bcol[nt], 0.0f);
                    hout[(size_t)r2 * D + col] = f2bf(val * dr);
                }
            } else {
                #pragma unroll
                for (int nt = 0; nt < 2; nt++) {
                    int col = wave * 32 + nt * 16 + lg;
                    hrelu[(size_t)r2 * D + col] = fmaxf(acc2[nt][i2] + bcol[nt], 0.0f);
                }
            }
        }
    }
}

// ---- segmented pooling, 4-way row-split per graph for latency hiding ----
__global__ __launch_bounds__(256) void k_pool(const float* __restrict__ hrelu,
                                              const int* __restrict__ gstart,
                                              const int* __restrict__ gcnt,
                                              float* __restrict__ pmax,
                                              float* __restrict__ psum, int B) {
    int g = blockIdx.x >> 2;
    int q = blockIdx.x & 3;
    int c = threadIdx.x & 127;
    int p = threadIdx.x >> 7;
    int start = gstart[g];
    int endr = start + gcnt[g];

    float mx0 = 0.f, mx1 = 0.f, sm0 = 0.f, sm1 = 0.f;
    int r = start + q * 2 + p;
    for (; r + 8 < endr; r += 16) {
        float v0 = __builtin_nontemporal_load(hrelu + (size_t)r * D + c);
        float v1 = __builtin_nontemporal_load(hrelu + (size_t)(r + 8) * D + c);
        mx0 = fmaxf(mx0, v0); sm0 += v0;
        mx1 = fmaxf(mx1, v1); sm1 += v1;
    }
    if (r < endr) {
        float v0 = __builtin_nontemporal_load(hrelu + (size_t)r * D + c);
        mx0 = fmaxf(mx0, v0); sm0 += v0;
    }
    float mx = fmaxf(mx0, mx1), sm = sm0 + sm1;

    __shared__ float smx[128], ssm[128];
    if (p == 1) { smx[c] = mx; ssm[c] = sm; }
    __syncthreads();
    if (p == 0) {
        pmax[((size_t)q * B + g) * D + c] = fmaxf(mx, smx[c]);
        psum[((size_t)q * B + g) * D + c] = sm + ssm[c];
    }
}

// ---- final: combine 4 partials; out[g] = [gmax, gsum/cnt, gsum] @ out_w + out_b ----
__global__ void k_final(const float* __restrict__ pmax, const float* __restrict__ psum,
                        const int* __restrict__ gcnt, const float* __restrict__ ow,
                        const float* __restrict__ ob, float* __restrict__ out, int B) {
    int g = blockIdx.x;
    int t = threadIdx.x;  // 64
    float part[10];
    #pragma unroll
    for (int o = 0; o < 10; o++) part[o] = 0.f;
    float invc = 1.0f / fmaxf((float)gcnt[g], 1.0f);
    for (int k = t; k < 3 * D; k += 64) {
        int c = (k < D) ? k : ((k < 2 * D) ? k - D : k - 2 * D);
        float pk;
        if (k < D) {
            float m = pmax[(size_t)g * D + c];
            #pragma unroll
            for (int q = 1; q < 4; q++) m = fmaxf(m, pmax[((size_t)q * B + g) * D + c]);
            pk = m;
        } else {
            float s = psum[(size_t)g * D + c];
            #pragma unroll
            for (int q = 1; q < 4; q++) s += psum[((size_t)q * B + g) * D + c];
            pk = (k < 2 * D) ? s * invc : s;
        }
        const float* w = ow + k * 10;
        #pragma unroll
        for (int o = 0; o < 10; o++) part[o] += pk * w[o];
    }
    #pragma unroll
    for (int off = 32; off > 0; off >>= 1)
        #pragma unroll
        for (int o = 0; o < 10; o++) part[o] += __shfl_down(part[o], off, 64);
    if (t == 0)
        #pragma unroll
        for (int o = 0; o < 10; o++) out[g * 10 + o] = part[o] + ob[o];
}

extern "C" void kernel_launch(void* const* d_in, const int* in_sizes, int n_in,
                              void* d_out, int out_size, void* d_ws, size_t ws_size,
                              hipStream_t stream) {
    const float* x     = (const float*)d_in[0];
    const int*   ei    = (const int*)d_in[1];
    const int*   batch = (const int*)d_in[2];
    const float* convw = (const float*)d_in[3];
    const float* convb = (const float*)d_in[4];
    const float* outw  = (const float*)d_in[5];
    const float* outb  = (const float*)d_in[6];
    float* out = (float*)d_out;

    const int N = in_sizes[0] / D;        // 100000
    const int E = in_sizes[1] / 2;        // 1600000
    const int L = in_sizes[3] / (D * D);  // 3
    const int B = out_size / 10;          // 256

    const int* src = ei;
    const int* dst = ei + E;

    const int KBE   = (N + DPB - 1) / DPB;     // coarse buckets (1563)
    const int nkeys = KBE * KPB;               // global fine-key space
    const int totw  = L * D * D;               // 49152 (192 blocks)
    const int EB    = (E + 255) / 256;         // edge blocks (6250)

    char* p = (char*)d_ws;
    auto alloc = [&](size_t bytes) { char* r = p; p += (bytes + 255) & ~255ull; return r; };
    short* hb0     = (short*)alloc((size_t)N * D * 2);      // ping-pong bf16 rows
    short* hb1     = (short*)alloc((size_t)N * D * 2);
    float* hrelu   = (float*)alloc((size_t)N * D * 4);      // fp32 last-layer relu; ALIASED as staging
    short* Wt      = (short*)alloc((size_t)L * D * D * 2);  // bf16 W^T
    int*   row_ptr = (int*)alloc(((size_t)nkeys + 1) * 4);
    int*   csr_src = (int*)alloc((size_t)E * 4);
    int*   bcnt    = (int*)alloc((size_t)SUB * KBE * 4);
    int*   bbase   = (int*)alloc(((size_t)KBE + 1) * 4);
    float* dinv    = (float*)alloc((size_t)N * 4);
    float* pmax    = (float*)alloc((size_t)4 * B * D * 4);
    float* psum    = (float*)alloc((size_t)4 * B * D * 4);
    int*   gcnt    = (int*)alloc((size_t)B * 4);
    int*   gstart  = (int*)alloc(((size_t)B + 1) * 4);

    // staging: SUB*KBE*CAP_SUB*4 = 64*1563*64*4 = 25.6 MB <= hrelu's 51.2 MB
    int* staging = (int*)hrelu;   // hrelu written only after k_build completes

    hipMemsetAsync(bcnt, 0, (size_t)SUB * KBE * 4, stream);

    // fused: edge bucketing + cvt_w + gseg (tail blocks)
    k_bucket<<<EB + totw / 256 + 1, 256, 0, stream>>>(src, dst, bcnt, staging, E, KBE,
                                                      convw, Wt, totw,
                                                      batch, gstart, gcnt, N, B);
    k_bscan<<<1, 512, 0, stream>>>(bcnt, bbase, row_ptr, nkeys, KBE);
    k_build<<<KBE, 256, 0, stream>>>(staging, bcnt, bbase, row_ptr, csr_src, dinv, N, KBE);
    k_cvt_x<<<((N * D / 4) + 255) / 256, 256, 0, stream>>>(x, dinv, hb0, N * D / 4);

    const int lblocks = (N + 15) / 16;
    // layer 0: hb0 -> hb1 ; layer 1: hb1 -> hb0 ; layer 2: hb0 -> hrelu
    k_layer<<<lblocks, 256, 0, stream>>>(hb0, row_ptr, csr_src, dinv, Wt,
                                         convb, hb1, hrelu, N, 0);
    k_layer<<<lblocks, 256, 0, stream>>>(hb1, row_ptr, csr_src, dinv, Wt + D * D,
                                         convb + D, hb0, hrelu, N, 0);
    k_layer<<<lblocks, 256, 0, stream>>>(hb0, row_ptr, csr_src, dinv, Wt + 2 * D * D,
                                         convb + 2 * D, hb1, hrelu, N, 1);

    k_pool<<<B * 4, 256, 0, stream>>>(hrelu, gstart, gcnt, pmax, psum, B);
    k_final<<<B, 64, 0, stream>>>(pmax, psum, gcnt, outw, outb, out, B);
}

// Round 11
// 453.765 us; speedup vs baseline: 1.2431x; 1.0005x over previous
//
#include <hip/hip_runtime.h>
#include <hip/hip_bf16.h>

#define D 128
#define NP 8           // src-range sub-buckets per dst (csr slice order)
#define DPB 64         // dst per coarse bucket (b = d>>6)
#define KPB (DPB * NP) // fine keys per bucket = 512
#define RPS (KPB + 1)  // row_ptr stride per bucket (own end slot -> no global scan)
#define SUB 64         // sub-cursors per bucket
#define CAP_SUB 64     // staging capacity per (sub, bucket); mean 16

typedef __attribute__((ext_vector_type(8))) __bf16 bf16x8;
typedef __attribute__((ext_vector_type(4))) float f32x4;
typedef __attribute__((ext_vector_type(4))) short s16x4;
typedef __attribute__((ext_vector_type(8))) short s16x8;

static __device__ __forceinline__ short f2bf(float f) {
    union { float f; unsigned u; } in; in.f = f;
    unsigned u = in.u;
    u += 0x7fffu + ((u >> 16) & 1u);   // round-to-nearest-even
    return (short)(u >> 16);
}

// ---- phase 1 (FUSED): coarse-bucket edges + cvt_w + gseg tail blocks ----
// pack: fineKey(9b: (d&63)*8 + (src>>14)) << 17 | src(17b)   [N < 2^17]
__global__ void k_bucket(const int* __restrict__ src, const int* __restrict__ dst,
                         int* __restrict__ bcnt, int* __restrict__ staging,
                         int E, int KBE,
                         const float* __restrict__ W, short* __restrict__ Wt, int totw,
                         const int* __restrict__ batch, int* __restrict__ gstart,
                         int* __restrict__ gcnt, int N, int B) {
    const int EB = (E + 255) >> 8;
    if (blockIdx.x < (unsigned)EB) {
        int i = blockIdx.x * 256 + threadIdx.x;
        if (i >= E) return;
        int d = __builtin_nontemporal_load(dst + i);
        int s = __builtin_nontemporal_load(src + i);
        int b = d >> 6;
        int key = ((d & 63) << 3) | (s >> 14);
        int j = blockIdx.x & (SUB - 1);      // j%8 == heuristic XCD
        int slot = atomicAdd(&bcnt[j * KBE + b], 1);
        if (slot < CAP_SUB) staging[((size_t)j * KBE + b) * CAP_SUB + slot] = (key << 17) | s;
    } else if ((int)blockIdx.x - EB < (totw >> 8)) {
        // conv_w: fp32 [L][k][n] -> bf16 transposed [L][n][k]
        int i = (blockIdx.x - EB) * 256 + threadIdx.x;
        if (i < totw) {
            int l = i >> 14;
            int rem = i & 16383;
            int n = rem >> 7;
            int k = rem & 127;
            Wt[i] = f2bf(W[(l << 14) + (k << 7) + n]);
        }
    } else {
        // batch is SORTED: segment starts AND counts via binary search
        for (int g = threadIdx.x; g <= B; g += 256) {
            int lo = 0, hi = N;
            while (lo < hi) {
                int mid = (lo + hi) >> 1;
                if (batch[mid] < g) lo = mid + 1; else hi = mid;
            }
            gstart[g] = lo;
            if (g < B) {
                int lo2 = lo, hi2 = N;
                while (lo2 < hi2) {
                    int mid = (lo2 + hi2) >> 1;
                    if (batch[mid] < g + 1) lo2 = mid + 1; else hi2 = mid;
                }
                gcnt[g] = lo2 - lo;
            }
        }
    }
}

// ---- phase 2 (FUSED): fine CSR build + atomic region claim + cvt_x ----
// No inter-bucket scan: each bucket's csr region base comes from one
// atomicAdd on a global cursor (region ORDER is arbitrary; regions are
// disjoint+contiguous, which is all k_layer needs). row_ptr stride RPS
// gives each bucket its own end slot. Also converts this block's 64 x-rows
// to pre-scaled bf16 (dinv staged in LDS) -- k_cvt_x launch eliminated.
__global__ __launch_bounds__(256) void k_build(
    const int* __restrict__ staging, const int* __restrict__ bcnt,
    int* __restrict__ row_ptr, int* __restrict__ csr_src,
    float* __restrict__ dinv, int* __restrict__ cursor,
    const float* __restrict__ x, short* __restrict__ xb, int N, int KBE)
{
    const int b = blockIdx.x;
    const int tid = threadIdx.x;
    __shared__ int cnt[KPB];
    __shared__ int subn[SUB];
    __shared__ int wtot[4];
    __shared__ int base_s, tot_s;
    __shared__ float dinv_s[DPB];

    if (tid < SUB) {
        int c = bcnt[tid * KBE + b];
        subn[tid] = (c > CAP_SUB) ? CAP_SUB : c;
    }
    for (int k = tid; k < KPB; k += 256) cnt[k] = 0;
    __syncthreads();

    const int j = tid >> 2, l4 = tid & 3;
    const int* __restrict__ sreg = staging + ((size_t)j * KBE + b) * CAP_SUB;
    const int sn = subn[j];

    // histogram over fine keys
    for (int e = l4; e < sn; e += 4)
        atomicAdd(&cnt[sreg[e] >> 17], 1);
    __syncthreads();

    // exclusive scan of cnt[0..512): 2 elems/thread, wave shuffle scan
    {
        const int w = tid >> 6, lane = tid & 63;
        const int e0 = cnt[2 * tid], e1 = cnt[2 * tid + 1];
        const int s = e0 + e1;
        int is = s;
        #pragma unroll
        for (int off = 1; off < 64; off <<= 1) {
            int xs = __shfl_up(is, off, 64);
            if (lane >= off) is += xs;
        }
        if (lane == 63) wtot[w] = is;
        __syncthreads();
        if (tid == 0) {
            int run = 0;
            #pragma unroll
            for (int i = 0; i < 4; i++) { int xv = wtot[i]; wtot[i] = run; run += xv; }
        }
        __syncthreads();
        const int excl = is - s + wtot[w];
        cnt[2 * tid] = excl;
        cnt[2 * tid + 1] = excl + e0;
        if (tid == 255) tot_s = is + wtot[3];   // bucket total
        __syncthreads();
        if (tid == 0) base_s = atomicAdd(cursor, tot_s);
        __syncthreads();
    }
    const int base = base_s;
    const int tot = tot_s;

    int* __restrict__ rp = row_ptr + (size_t)b * RPS;
    for (int k = tid; k < KPB; k += 256) rp[k] = base + cnt[k];
    if (tid == 0) rp[KPB] = base + tot;
    for (int dl = tid; dl < DPB; dl += 256) {
        int d = b * DPB + dl;
        if (d < N) {
            int hi2 = (dl == DPB - 1) ? tot : cnt[(dl + 1) * NP];
            int deg = hi2 - cnt[dl * NP];
            float dv = rsqrtf((float)deg + 1.0f);
            dinv[d] = dv;
            dinv_s[dl] = dv;
        }
    }
    __syncthreads();

    // scatter into this bucket's contiguous csr region (LDS cursors)
    for (int e = l4; e < sn; e += 4) {
        int wd = sreg[e];
        int slot = base + atomicAdd(&cnt[wd >> 17], 1);
        csr_src[slot] = wd & 0x1FFFF;
    }

    // fused cvt_x: this block's 64 nodes, x' = dinv * x -> bf16
    // (dinv_s written before the barrier above; no extra sync needed)
    for (int idx = tid; idx < DPB * 32; idx += 256) {
        const int dl = idx >> 5;
        const int d = b * DPB + dl;
        if (d < N) {
            f32x4 v = __builtin_nontemporal_load((const f32x4*)x + (size_t)d * 32 + (idx & 31));
            const float dv = dinv_s[dl];
            s16x4 o;
            o.x = f2bf(v.x * dv); o.y = f2bf(v.y * dv);
            o.z = f2bf(v.z * dv); o.w = f2bf(v.w * dv);
            ((s16x4*)xb)[(size_t)d * 32 + (idx & 31)] = o;
        }
    }
}

// ---- FUSED layer (r3-exact math; row_ptr uses per-bucket stride RPS) ----
// 16 nodes/block, 8-deep pipelined gather chains, 1 barrier, 16x128 MFMA GEMM.
// Floor established over 8 variants (r0-r9): random-gather line-rate limit.
// mode 0: hout[r] = bf16( relu(C + b) * dinv[r] );  mode 1: hrelu[r] = fp32 relu(C+b)
__global__ __launch_bounds__(256) void k_layer(
    const short* __restrict__ hin, const int* __restrict__ row_ptr,
    const int* __restrict__ csr_src, const float* __restrict__ dinv,
    const short* __restrict__ Wt, const float* __restrict__ bias,
    short* __restrict__ hout, float* __restrict__ hrelu, int N, int mode)
{
    __shared__ __align__(16) short tile[16 * 128];   // 4 KB, swizzled 16B chunks
    const int tid = threadIdx.x;
    const int wave = tid >> 6;
    const int lane = tid & 63;
    const int group = lane >> 4;
    const int lg = lane & 15;
    const int off = lg * 8;
    const int node_base = blockIdx.x * 16;
    const int r = wave * 4 + group;          // tile row this group owns (0..15)
    const int i = node_base + r;

    // ---- phase 1: aggregate one node per group (16 concurrent per block) ----
    short* dstp = &tile[r * 128 + ((lg ^ (r & 7)) << 3)];
    if (i < N) {
        float acc[8];
        bf16x8 v = *(const bf16x8*)(hin + (size_t)i * D + off);
        #pragma unroll
        for (int k = 0; k < 8; k++) acc[k] = (float)v[k];

        const int rb = (i >> 6) * RPS + (i & 63) * NP;
        int t = row_ptr[rb];
        const int end = row_ptr[rb + NP];
        const int nfull = (end - t) >> 3;    // full 8-chains

        int i0, i1, i2, i3, i4, i5, i6, i7;
        if (nfull > 0) {
            i0 = csr_src[t + 0]; i1 = csr_src[t + 1];
            i2 = csr_src[t + 2]; i3 = csr_src[t + 3];
            i4 = csr_src[t + 4]; i5 = csr_src[t + 5];
            i6 = csr_src[t + 6]; i7 = csr_src[t + 7];
        }
        #pragma unroll 1
        for (int c = 0; c < nfull; c++) {
            bf16x8 v0 = *(const bf16x8*)(hin + (size_t)i0 * D + off);
            bf16x8 v1 = *(const bf16x8*)(hin + (size_t)i1 * D + off);
            bf16x8 v2 = *(const bf16x8*)(hin + (size_t)i2 * D + off);
            bf16x8 v3 = *(const bf16x8*)(hin + (size_t)i3 * D + off);
            bf16x8 v4 = *(const bf16x8*)(hin + (size_t)i4 * D + off);
            bf16x8 v5 = *(const bf16x8*)(hin + (size_t)i5 * D + off);
            bf16x8 v6 = *(const bf16x8*)(hin + (size_t)i6 * D + off);
            bf16x8 v7 = *(const bf16x8*)(hin + (size_t)i7 * D + off);
            t += 8;
            if (c + 1 < nfull) {             // prefetch next indices while rows fly
                i0 = csr_src[t + 0]; i1 = csr_src[t + 1];
                i2 = csr_src[t + 2]; i3 = csr_src[t + 3];
                i4 = csr_src[t + 4]; i5 = csr_src[t + 5];
                i6 = csr_src[t + 6]; i7 = csr_src[t + 7];
            }
            #pragma unroll
            for (int k = 0; k < 8; k++)
                acc[k] += ((((float)v0[k] + (float)v1[k]) + ((float)v2[k] + (float)v3[k]))
                         + (((float)v4[k] + (float)v5[k]) + ((float)v6[k] + (float)v7[k])));
        }
        for (; t + 4 <= end; t += 4) {       // 4-deep tail
            int j0 = csr_src[t + 0], j1 = csr_src[t + 1];
            int j2 = csr_src[t + 2], j3 = csr_src[t + 3];
            bf16x8 v0 = *(const bf16x8*)(hin + (size_t)j0 * D + off);
            bf16x8 v1 = *(const bf16x8*)(hin + (size_t)j1 * D + off);
            bf16x8 v2 = *(const bf16x8*)(hin + (size_t)j2 * D + off);
            bf16x8 v3 = *(const bf16x8*)(hin + (size_t)j3 * D + off);
            #pragma unroll
            for (int k = 0; k < 8; k++)
                acc[k] += (((float)v0[k] + (float)v1[k]) + ((float)v2[k] + (float)v3[k]));
        }
        for (; t < end; t++) {               // scalar tail (<=3)
            int j0 = csr_src[t];
            bf16x8 v0 = *(const bf16x8*)(hin + (size_t)j0 * D + off);
            #pragma unroll
            for (int k = 0; k < 8; k++) acc[k] += (float)v0[k];
        }

        const float di = dinv[i];
        s16x8 o;
        #pragma unroll
        for (int k = 0; k < 8; k++) o[k] = f2bf(acc[k] * di);
        *(s16x8*)dstp = o;
    } else {
        s16x8 z = {0, 0, 0, 0, 0, 0, 0, 0};
        *(s16x8*)dstp = z;
    }
    __syncthreads();

    // ---- phase 2: cooperative GEMM; wave w computes cols [w*32, w*32+32) ----
    bf16x8 afrag[4];
    #pragma unroll
    for (int kt = 0; kt < 4; kt++)
        afrag[kt] = *(const bf16x8*)(&tile[lg * 128 + (((group + 4 * kt) ^ (lg & 7)) << 3)]);

    f32x4 acc2[2];
    #pragma unroll
    for (int nt = 0; nt < 2; nt++) { f32x4 z = {0.f, 0.f, 0.f, 0.f}; acc2[nt] = z; }
    #pragma unroll
    for (int nt = 0; nt < 2; nt++) {
        const short* bp = Wt + (size_t)(wave * 32 + nt * 16 + lg) * D + group * 8;
        #pragma unroll
        for (int kt = 0; kt < 4; kt++) {
            bf16x8 b = *(const bf16x8*)(bp + kt * 32);
            acc2[nt] = __builtin_amdgcn_mfma_f32_16x16x32_bf16(afrag[kt], b, acc2[nt], 0, 0, 0);
        }
    }

    // C/D layout: col = lane&15, row = (lane>>4)*4 + reg
    float bcol[2];
    #pragma unroll
    for (int nt = 0; nt < 2; nt++) bcol[nt] = bias[wave * 32 + nt * 16 + lg];
    const int row0 = node_base + group * 4;
    #pragma unroll
    for (int i2 = 0; i2 < 4; i2++) {
        int r2 = row0 + i2;
        if (r2 < N) {
            if (mode == 0) {
                float dr = dinv[r2];
                #pragma unroll
                for (int nt = 0; nt < 2; nt++) {
                    int col = wave * 32 + nt * 16 + lg;
                    float val = fmaxf(acc2[nt][i2] + bcol[nt], 0.0f);
                    hout[(size_t)r2 * D + col] = f2bf(val * dr);
                }
            } else {
                #pragma unroll
                for (int nt = 0; nt < 2; nt++) {
                    int col = wave * 32 + nt * 16 + lg;
                    hrelu[(size_t)r2 * D + col] = fmaxf(acc2[nt][i2] + bcol[nt], 0.0f);
                }
            }
        }
    }
}

// ---- segmented pooling, 4-way row-split per graph for latency hiding ----
__global__ __launch_bounds__(256) void k_pool(const float* __restrict__ hrelu,
                                              const int* __restrict__ gstart,
                                              const int* __restrict__ gcnt,
                                              float* __restrict__ pmax,
                                              float* __restrict__ psum, int B) {
    int g = blockIdx.x >> 2;
    int q = blockIdx.x & 3;
    int c = threadIdx.x & 127;
    int p = threadIdx.x >> 7;
    int start = gstart[g];
    int endr = start + gcnt[g];

    float mx0 = 0.f, mx1 = 0.f, sm0 = 0.f, sm1 = 0.f;
    int r = start + q * 2 + p;
    for (; r + 8 < endr; r += 16) {
        float v0 = __builtin_nontemporal_load(hrelu + (size_t)r * D + c);
        float v1 = __builtin_nontemporal_load(hrelu + (size_t)(r + 8) * D + c);
        mx0 = fmaxf(mx0, v0); sm0 += v0;
        mx1 = fmaxf(mx1, v1); sm1 += v1;
    }
    if (r < endr) {
        float v0 = __builtin_nontemporal_load(hrelu + (size_t)r * D + c);
        mx0 = fmaxf(mx0, v0); sm0 += v0;
    }
    float mx = fmaxf(mx0, mx1), sm = sm0 + sm1;

    __shared__ float smx[128], ssm[128];
    if (p == 1) { smx[c] = mx; ssm[c] = sm; }
    __syncthreads();
    if (p == 0) {
        pmax[((size_t)q * B + g) * D + c] = fmaxf(mx, smx[c]);
        psum[((size_t)q * B + g) * D + c] = sm + ssm[c];
    }
}

// ---- final: combine 4 partials; out[g] = [gmax, gsum/cnt, gsum] @ out_w + out_b ----
__global__ void k_final(const float* __restrict__ pmax, const float* __restrict__ psum,
                        const int* __restrict__ gcnt, const float* __restrict__ ow,
                        const float* __restrict__ ob, float* __restrict__ out, int B) {
    int g = blockIdx.x;
    int t = threadIdx.x;  // 64
    float part[10];
    #pragma unroll
    for (int o = 0; o < 10; o++) part[o] = 0.f;
    float invc = 1.0f / fmaxf((float)gcnt[g], 1.0f);
    for (int k = t; k < 3 * D; k += 64) {
        int c = (k < D) ? k : ((k < 2 * D) ? k - D : k - 2 * D);
        float pk;
        if (k < D) {
            float m = pmax[(size_t)g * D + c];
            #pragma unroll
            for (int q = 1; q < 4; q++) m = fmaxf(m, pmax[((size_t)q * B + g) * D + c]);
            pk = m;
        } else {
            float s = psum[(size_t)g * D + c];
            #pragma unroll
            for (int q = 1; q < 4; q++) s += psum[((size_t)q * B + g) * D + c];
            pk = (k < 2 * D) ? s * invc : s;
        }
        const float* w = ow + k * 10;
        #pragma unroll
        for (int o = 0; o < 10; o++) part[o] += pk * w[o];
    }
    #pragma unroll
    for (int off = 32; off > 0; off >>= 1)
        #pragma unroll
        for (int o = 0; o < 10; o++) part[o] += __shfl_down(part[o], off, 64);
    if (t == 0)
        #pragma unroll
        for (int o = 0; o < 10; o++) out[g * 10 + o] = part[o] + ob[o];
}

extern "C" void kernel_launch(void* const* d_in, const int* in_sizes, int n_in,
                              void* d_out, int out_size, void* d_ws, size_t ws_size,
                              hipStream_t stream) {
    const float* x     = (const float*)d_in[0];
    const int*   ei    = (const int*)d_in[1];
    const int*   batch = (const int*)d_in[2];
    const float* convw = (const float*)d_in[3];
    const float* convb = (const float*)d_in[4];
    const float* outw  = (const float*)d_in[5];
    const float* outb  = (const float*)d_in[6];
    float* out = (float*)d_out;

    const int N = in_sizes[0] / D;        // 100000
    const int E = in_sizes[1] / 2;        // 1600000
    const int L = in_sizes[3] / (D * D);  // 3
    const int B = out_size / 10;          // 256

    const int* src = ei;
    const int* dst = ei + E;

    const int KBE   = (N + DPB - 1) / DPB;     // coarse buckets (1563)
    const int totw  = L * D * D;               // 49152 (192 blocks)
    const int EB    = (E + 255) / 256;         // edge blocks (6250)

    char* p = (char*)d_ws;
    auto alloc = [&](size_t bytes) { char* r = p; p += (bytes + 255) & ~255ull; return r; };
    short* hb0     = (short*)alloc((size_t)N * D * 2);      // ping-pong bf16 rows
    short* hb1     = (short*)alloc((size_t)N * D * 2);
    float* hrelu   = (float*)alloc((size_t)N * D * 4);      // fp32 last-layer relu; ALIASED as staging
    short* Wt      = (short*)alloc((size_t)L * D * D * 2);  // bf16 W^T
    int*   row_ptr = (int*)alloc((size_t)KBE * RPS * 4);    // per-bucket stride 513
    int*   csr_src = (int*)alloc((size_t)E * 4);
    int*   bcnt    = (int*)alloc(((size_t)SUB * KBE + 64) * 4);  // + cursor tail
    float* dinv    = (float*)alloc((size_t)N * 4);
    float* pmax    = (float*)alloc((size_t)4 * B * D * 4);
    float* psum    = (float*)alloc((size_t)4 * B * D * 4);
    int*   gcnt    = (int*)alloc((size_t)B * 4);
    int*   gstart  = (int*)alloc(((size_t)B + 1) * 4);

    int* cursor = bcnt + (size_t)SUB * KBE;    // zeroed by the same memset

    // staging: SUB*KBE*CAP_SUB*4 = 64*1563*64*4 = 25.6 MB <= hrelu's 51.2 MB
    int* staging = (int*)hrelu;   // hrelu written only after k_build completes

    hipMemsetAsync(bcnt, 0, ((size_t)SUB * KBE + 64) * 4, stream);

    // fused: edge bucketing + cvt_w + gseg (tail blocks)
    k_bucket<<<EB + totw / 256 + 1, 256, 0, stream>>>(src, dst, bcnt, staging, E, KBE,
                                                      convw, Wt, totw,
                                                      batch, gstart, gcnt, N, B);
    // fused: CSR build (atomic region claim, no scan kernel) + cvt_x
    k_build<<<KBE, 256, 0, stream>>>(staging, bcnt, row_ptr, csr_src, dinv, cursor,
                                     x, hb0, N, KBE);

    const int lblocks = (N + 15) / 16;
    // layer 0: hb0 -> hb1 ; layer 1: hb1 -> hb0 ; layer 2: hb0 -> hrelu
    k_layer<<<lblocks, 256, 0, stream>>>(hb0, row_ptr, csr_src, dinv, Wt,
                                         convb, hb1, hrelu, N, 0);
    k_layer<<<lblocks, 256, 0, stream>>>(hb1, row_ptr, csr_src, dinv, Wt + D * D,
                                         convb + D, hb0, hrelu, N, 0);
    k_layer<<<lblocks, 256, 0, stream>>>(hb0, row_ptr, csr_src, dinv, Wt + 2 * D * D,
                                         convb + 2 * D, hb1, hrelu, N, 1);

    k_pool<<<B * 4, 256, 0, stream>>>(hrelu, gstart, gcnt, pmax, psum, B);
    k_final<<<B, 64, 0, stream>>>(pmax, psum, gcnt, outw, outb, out, B);
}